// Round 8
// baseline (893.827 us; speedup 1.0000x reference)
//
#include <hip/hip_runtime.h>
#include <hip/hip_bf16.h>
#include <hip/hip_fp16.h>
#include <cstdio>

#define N_NODES 10000
#define M_NODEP 10240            // 40*256
#define N_EDGES 50000
#define M_EDGEP 50176            // 196*256
#define E_AUG   60000
#define E_AUGP  60160            // 235*256
#define ED      16
#define BI_OUT  272
#define KP      288              // 272 padded to 9*32

typedef __attribute__((ext_vector_type(8))) short s16x8;   // 8 bf16 (4 VGPRs)
typedef __attribute__((ext_vector_type(4))) short s16x4;
typedef __attribute__((ext_vector_type(8))) _Float16 h16x8;
typedef __attribute__((ext_vector_type(4))) _Float16 h16x4;
typedef __attribute__((ext_vector_type(4))) float f32x4;

__device__ inline void stc(float* p, float v){ *p = v; }
__device__ inline void stc(__hip_bfloat16* p, float v){ *p = __float2bfloat16(v); }
__device__ inline void stc(__half* p, float v){ *p = __float2half(v); }
__device__ inline float bf2f(short s){ return __uint_as_float(((unsigned)(unsigned short)s) << 16); }
__device__ inline short f2bf(float f){ __hip_bfloat16 h = __float2bfloat16(f); return *(short*)&h; }

// async global->LDS, 16 B per lane; LDS dest is wave-uniform base (lane*16 implicit)
__device__ __forceinline__ void gl2lds16(const void* g, void* l){
  __builtin_amdgcn_global_load_lds((const __attribute__((address_space(1))) void*)g,
                                   (__attribute__((address_space(3))) void*)l, 16, 0, 0);
}

// ---------- mean edge_attr per dst (self-loop fill) ----------
__global__ void edge_attr_sum_k(const float* __restrict__ ea, const int* __restrict__ ei,
                                float* __restrict__ meanat, float* __restrict__ cntF){
  int t = blockIdx.x*256 + threadIdx.x;
  if (t >= N_EDGES*ED) return;
  int e = t >> 4, j = t & 15;
  int dst = ei[N_EDGES + e];
  atomicAdd(&meanat[dst*ED + j], ea[t]);
  if (j == 0) atomicAdd(&cntF[dst], 1.0f);
}

__global__ void mean_div_k(float* __restrict__ meanat, const float* __restrict__ cntF){
  int t = blockIdx.x*256 + threadIdx.x;
  if (t >= N_NODES*ED) return;
  meanat[t] /= fmaxf(cntF[t>>4], 1.0f);
}

// ---------- CSR build ----------
__global__ void scan_k(const float* __restrict__ cntF, int* __restrict__ rowptr){
  __shared__ int s[1024];
  int tid = threadIdx.x;
  int loc[10]; int sum = 0;
  #pragma unroll
  for (int k = 0; k < 10; ++k){
    int i = tid*10 + k;
    int v = (i < N_NODES) ? ((int)cntF[i] + 1) : 0;   // +1 self loop
    loc[k] = sum; sum += v;
  }
  s[tid] = sum; __syncthreads();
  for (int off = 1; off < 1024; off <<= 1){
    int t2 = (tid >= off) ? s[tid-off] : 0;
    __syncthreads();
    s[tid] += t2;
    __syncthreads();
  }
  int pre = s[tid] - sum;
  #pragma unroll
  for (int k = 0; k < 10; ++k){
    int i = tid*10 + k;
    if (i < N_NODES) rowptr[i] = pre + loc[k];
  }
  if (tid == 1023) rowptr[N_NODES] = s[1023];
}

__global__ void scatter_k(const int* __restrict__ ei, const int* __restrict__ rowptr,
                          int* __restrict__ fill, int* __restrict__ csr){
  int e = blockIdx.x*256 + threadIdx.x;
  if (e >= E_AUG) return;
  int dst = (e < N_EDGES) ? ei[N_EDGES+e] : (e - N_EDGES);
  int pos = rowptr[dst] + atomicAdd(&fill[dst], 1);
  csr[pos] = e;
}

// ---------- MFMA bf16 GEMM, 256x128 tile: C[M,N] = A[M,K] @ B^T[N,K]^T ----------
// LDS element offset (row,quad) = row*32 + ((quad+(row>>1))&3)*8 -> 2-way only.
// Staging lane l (rl=l>>2, cq=l&3): chunk l of a 16-row region; global source
// row R+rl, quad (cq-((rl>>1)&3))&3 -> each row one 64B segment. Wave w stages
// A rows [w*64,w*64+64) (4 regions) and B rows [w*32,w*32+32) (2 regions).
template<typename TC, bool BIAS, bool RELU>
__global__ __launch_bounds__(256)
void mfma_gemm_k(const __hip_bfloat16* __restrict__ A, const __hip_bfloat16* __restrict__ Bt,
                 TC* __restrict__ C, const float* __restrict__ bias,
                 int Mstore, int K, int lda, int ldb, int ldc){
  __shared__ __align__(16) __hip_bfloat16 Asm[8192];   // 256 x 32
  __shared__ __align__(16) __hip_bfloat16 Bsm[4096];   // 128 x 32
  const int tid = threadIdx.x;
  const int lane = tid & 63, wave = tid >> 6;
  const int m0 = blockIdx.x * 256, n0 = blockIdx.y * 128;
  const int quad = lane >> 4, r16 = lane & 15;

  f32x4 acc[4][8];
  #pragma unroll
  for (int i = 0; i < 4; ++i)
    #pragma unroll
    for (int j = 0; j < 8; ++j)
      acc[i][j] = (f32x4){0.f, 0.f, 0.f, 0.f};

  const int rl = lane >> 2, cq = lane & 3;
  const int qg = (cq - ((rl >> 1) & 3)) & 3;
  const __hip_bfloat16* ga[4];
  const __hip_bfloat16* gb[2];
  #pragma unroll
  for (int r = 0; r < 4; ++r)
    ga[r] = &A[(size_t)(m0 + wave*64 + r*16 + rl)*lda + qg*8];
  #pragma unroll
  for (int r = 0; r < 2; ++r)
    gb[r] = &Bt[(size_t)(n0 + wave*32 + r*16 + rl)*ldb + qg*8];
  __hip_bfloat16* lA[4];
  __hip_bfloat16* lB[2];
  #pragma unroll
  for (int r = 0; r < 4; ++r) lA[r] = &Asm[(wave*64 + r*16)*32];
  #pragma unroll
  for (int r = 0; r < 2; ++r) lB[r] = &Bsm[(wave*32 + r*16)*32];

  for (int k0 = 0; k0 < K; k0 += 32){
    #pragma unroll
    for (int r = 0; r < 4; ++r) gl2lds16(ga[r] + k0, lA[r]);
    #pragma unroll
    for (int r = 0; r < 2; ++r) gl2lds16(gb[r] + k0, lB[r]);
    __syncthreads();
    s16x8 af[4], bf[8];
    #pragma unroll
    for (int i = 0; i < 4; ++i){
      int row = wave*64 + i*16 + r16;
      af[i] = *(const s16x8*)&Asm[row*32 + (((quad + (row >> 1)) & 3) << 3)];
    }
    #pragma unroll
    for (int j = 0; j < 8; ++j){
      int row = j*16 + r16;
      bf[j] = *(const s16x8*)&Bsm[row*32 + (((quad + (row >> 1)) & 3) << 3)];
    }
    #pragma unroll
    for (int i = 0; i < 4; ++i)
      #pragma unroll
      for (int j = 0; j < 8; ++j)
        acc[i][j] = __builtin_amdgcn_mfma_f32_16x16x32_bf16(af[i], bf[j], acc[i][j], 0, 0, 0);
    __syncthreads();
  }
  #pragma unroll
  for (int i = 0; i < 4; ++i){
    #pragma unroll
    for (int reg = 0; reg < 4; ++reg){
      int gr = m0 + wave*64 + i*16 + quad*4 + reg;
      if (gr >= Mstore) continue;
      #pragma unroll
      for (int j = 0; j < 8; ++j){
        int gc = n0 + j*16 + r16;
        float v = acc[i][j][reg];
        if (BIAS) v += bias[gc];
        if (RELU) v = fmaxf(v, 0.f);
        stc(&C[(size_t)gr*ldc + gc], v);
      }
    }
  }
}

// ---------- fused weight prep: WlWr^T (4 layers), We^T (4), MLP ----------
// WTa elem offsets: L0 0(16384) L1 16384(262144) L2 278528(524288) L3 802816(524288)
// WeTa: L0 0(8192) L1 8192(16384) L2 24576(16384) L3 40960(16384)
__global__ void prep_weights_k(
    const float* __restrict__ Wl0, const float* __restrict__ Wr0, const float* __restrict__ We0,
    const float* __restrict__ Wl1, const float* __restrict__ Wr1, const float* __restrict__ We1,
    const float* __restrict__ Wl2, const float* __restrict__ Wr2, const float* __restrict__ We2,
    const float* __restrict__ Wl3, const float* __restrict__ Wr3, const float* __restrict__ We3,
    const float* __restrict__ Wm1, const float* __restrict__ bm1,
    const float* __restrict__ Wm2, const float* __restrict__ bm2,
    __hip_bfloat16* __restrict__ WTa, __hip_bfloat16* __restrict__ WeTa,
    __hip_bfloat16* __restrict__ Wm1T, __hip_bfloat16* __restrict__ Wm2T,
    float* __restrict__ bm1p, float* __restrict__ bm2p){
  int t = blockIdx.x*256 + threadIdx.x;
  if (t < 16384){
    int half = t >> 13, r = t & 8191, i = r >> 8, j = r & 255;
    WTa[(half*256 + j)*32 + i] = __float2bfloat16(half ? Wr0[r] : Wl0[r]);
  } else if (t < 278528){
    int u = t - 16384, half = u >> 17, r = u & 131071, i = r >> 9, j = r & 511;
    WTa[16384 + (half*512 + j)*256 + i] = __float2bfloat16(half ? Wr1[r] : Wl1[r]);
  } else if (t < 802816){
    int u = t - 278528, half = u >> 18, r = u & 262143, i = r >> 9, j = r & 511;
    WTa[278528 + (half*512 + j)*512 + i] = __float2bfloat16(half ? Wr2[r] : Wl2[r]);
  } else if (t < 1327104){
    int u = t - 802816, half = u >> 18, r = u & 262143, i = r >> 9, j = r & 511;
    WTa[802816 + (half*512 + j)*512 + i] = __float2bfloat16(half ? Wr3[r] : Wl3[r]);
  }
  if (t < 8192){
    int n = t >> 5, k = t & 31;
    WeTa[t] = __float2bfloat16((k < 16) ? We0[k*256 + n] : 0.f);
  } else if (t < 24576){
    int u = t - 8192, n = u >> 5, k = u & 31;
    WeTa[t] = __float2bfloat16((k < 16) ? We1[k*512 + n] : 0.f);
  } else if (t < 40960){
    int u = t - 24576, n = u >> 5, k = u & 31;
    WeTa[t] = __float2bfloat16((k < 16) ? We2[k*512 + n] : 0.f);
  } else if (t < 57344){
    int u = t - 40960, n = u >> 5, k = u & 31;
    WeTa[t] = __float2bfloat16((k < 16) ? We3[k*512 + n] : 0.f);
  }
  if (t < 384*KP){
    int n = t / KP, k = t - n*KP;
    Wm1T[t] = __float2bfloat16((n < BI_OUT && k < BI_OUT) ? Wm1[(size_t)k*BI_OUT + n] : 0.f);
  }
  if (t < 128*KP){
    int n = t / KP, k = t - n*KP;
    Wm2T[t] = __float2bfloat16((n < 32 && k < BI_OUT) ? Wm2[(size_t)k*32 + n] : 0.f);
  }
  if (t < 384) bm1p[t] = (t < BI_OUT) ? bm1[t] : 0.f;
  if (t < 128) bm2p[t] = (t < 32) ? bm2[t] : 0.f;
}

__global__ void cast_h_k(const float* __restrict__ h, __hip_bfloat16* __restrict__ hb, int K){
  int t = blockIdx.x*256 + threadIdx.x;
  if (t >= M_NODEP*K) return;
  int r = t / K;
  hb[t] = (r < N_NODES) ? __float2bfloat16(h[t]) : __float2bfloat16(0.f);
}

// ea_aug -> bf16 [E_AUGP x 32] (K padded 16->32)
__global__ void cast_ea_k(const float* __restrict__ ea, const float* __restrict__ meanat,
                          __hip_bfloat16* __restrict__ eab){
  int t = blockIdx.x*256 + threadIdx.x;
  if (t >= E_AUGP*32) return;
  int e = t >> 5, j = t & 31;
  float v = 0.f;
  if (j < 16){
    if (e < N_EDGES) v = ea[(size_t)e*ED + j];
    else if (e < E_AUG) v = meanat[(size_t)(e - N_EDGES)*ED + j];
  }
  eab[t] = __float2bfloat16(v);
}

// Wbi[k<272][i<1024][j<16] -> WtAll: per chunk c, rows base[c]+[0,cw)=L, +[cw,2cw)=R; col = i&511
__global__ void wbi_transpose_k(const float* __restrict__ Wbi, __hip_bfloat16* __restrict__ WtAll){
  int t = blockIdx.x*256 + threadIdx.x;
  if (t >= BI_OUT*1024*ED) return;
  int k = t >> 14, r = t & 16383;
  int i = r >> 4, j = r & 15;
  int c = (k < 96) ? 0 : ((k < 192) ? 1 : 2);
  int kb = c*96;
  int base = c*3072;
  int cw = (c < 2) ? 1536 : 1280;
  int row = base + ((i >= 512) ? cw : 0) + (k - kb)*16 + j;
  WtAll[(size_t)row*512 + (i & 511)] = __float2bfloat16(Wbi[t]);
}

// ---------- fused GAT: one-pass online softmax + aggregate, 1 wave per dst ----------
// d-indexing lane-blocked: d = lane*NI + i; 2-edge unrolled main loop.
template<int DOUT, bool RELU>
__global__ __launch_bounds__(256)
void gat_fused_k(const __hip_bfloat16* __restrict__ XLXR, const __half* __restrict__ EE,
                 const int* __restrict__ ei, const int* __restrict__ rowptr,
                 const int* __restrict__ csr, const float* __restrict__ att,
                 const float* __restrict__ b, __hip_bfloat16* __restrict__ hb){
  constexpr int NI = DOUT/64;
  constexpr int W2 = 2*DOUT;
  int wave = threadIdx.x >> 6, lane = threadIdx.x & 63;
  int n = blockIdx.x*4 + wave;
  if (n >= N_NODES) return;
  int r0 = rowptr[n], r1 = rowptr[n+1];
  int pp = r0 + lane;
  int e_l = 0, s_l = 0;
  if (pp < r1){
    e_l = csr[pp];
    s_l = (e_l < N_EDGES) ? ei[e_l] : (e_l - N_EDGES);
  }
  float xr[NI], at[NI], acc[NI];
  #pragma unroll
  for (int i = 0; i < NI; ++i){
    int d = lane*NI + i;
    xr[i]  = bf2f(((const short*)XLXR)[(size_t)n*W2 + DOUT + d]);
    at[i]  = att[d];
    acc[i] = 0.f;
  }
  float mrun = -1e30f, den = 0.f;
  int p = r0;
  for (; p + 1 < r1; p += 2){
    int i0 = p - r0, i1 = i0 + 1;
    int e0, s0, e1, s1;
    if (i1 < 64){
      e0 = __shfl(e_l, i0, 64); s0 = __shfl(s_l, i0, 64);
      e1 = __shfl(e_l, i1, 64); s1 = __shfl(s_l, i1, 64);
    } else {
      if (i0 < 64){ e0 = __shfl(e_l, i0, 64); s0 = __shfl(s_l, i0, 64); }
      else { e0 = csr[p]; s0 = (e0 < N_EDGES) ? ei[e0] : (e0 - N_EDGES); }
      e1 = csr[p+1]; s1 = (e1 < N_EDGES) ? ei[e1] : (e1 - N_EDGES);
    }
    const short* xp0 = (const short*)XLXR + (size_t)s0*W2 + lane*NI;
    const short* xp1 = (const short*)XLXR + (size_t)s1*W2 + lane*NI;
    const _Float16* ep0 = (const _Float16*)EE + (size_t)e0*DOUT + lane*NI;
    const _Float16* ep1 = (const _Float16*)EE + (size_t)e1*DOUT + lane*NI;
    float xl0[NI], xl1[NI];
    float a0 = 0.f, a1 = 0.f;
    if constexpr (NI == 8){
      s16x8 xv0 = *(const s16x8*)xp0; h16x8 ev0 = *(const h16x8*)ep0;
      s16x8 xv1 = *(const s16x8*)xp1; h16x8 ev1 = *(const h16x8*)ep1;
      #pragma unroll
      for (int i = 0; i < 8; ++i){
        xl0[i] = bf2f(xv0[i]); xl1[i] = bf2f(xv1[i]);
        float v0 = xl0[i] + xr[i] + (float)ev0[i];
        float v1 = xl1[i] + xr[i] + (float)ev1[i];
        v0 = (v0 > 0.f) ? v0 : 0.2f*v0;
        v1 = (v1 > 0.f) ? v1 : 0.2f*v1;
        a0 += at[i]*v0; a1 += at[i]*v1;
      }
    } else {
      s16x4 xv0 = *(const s16x4*)xp0; h16x4 ev0 = *(const h16x4*)ep0;
      s16x4 xv1 = *(const s16x4*)xp1; h16x4 ev1 = *(const h16x4*)ep1;
      #pragma unroll
      for (int i = 0; i < 4; ++i){
        xl0[i] = bf2f(xv0[i]); xl1[i] = bf2f(xv1[i]);
        float v0 = xl0[i] + xr[i] + (float)ev0[i];
        float v1 = xl1[i] + xr[i] + (float)ev1[i];
        v0 = (v0 > 0.f) ? v0 : 0.2f*v0;
        v1 = (v1 > 0.f) ? v1 : 0.2f*v1;
        a0 += at[i]*v0; a1 += at[i]*v1;
      }
    }
    #pragma unroll
    for (int off = 32; off; off >>= 1){
      a0 += __shfl_xor(a0, off, 64);
      a1 += __shfl_xor(a1, off, 64);
    }
    float mnew = fmaxf(mrun, fmaxf(a0, a1));
    float s = __expf(mrun - mnew);
    float w0 = __expf(a0 - mnew);
    float w1 = __expf(a1 - mnew);
    den = den*s + w0 + w1;
    #pragma unroll
    for (int i = 0; i < NI; ++i) acc[i] = acc[i]*s + w0*xl0[i] + w1*xl1[i];
    mrun = mnew;
  }
  if (p < r1){
    int i0 = p - r0;
    int e0, s0;
    if (i0 < 64){ e0 = __shfl(e_l, i0, 64); s0 = __shfl(s_l, i0, 64); }
    else { e0 = csr[p]; s0 = (e0 < N_EDGES) ? ei[e0] : (e0 - N_EDGES); }
    const short* xp0 = (const short*)XLXR + (size_t)s0*W2 + lane*NI;
    const _Float16* ep0 = (const _Float16*)EE + (size_t)e0*DOUT + lane*NI;
    float xl0[NI];
    float a0 = 0.f;
    #pragma unroll
    for (int i = 0; i < NI; ++i){
      xl0[i] = bf2f(xp0[i]);
      float v0 = xl0[i] + xr[i] + (float)ep0[i];
      v0 = (v0 > 0.f) ? v0 : 0.2f*v0;
      a0 += at[i]*v0;
    }
    #pragma unroll
    for (int off = 32; off; off >>= 1) a0 += __shfl_xor(a0, off, 64);
    float mnew = fmaxf(mrun, a0);
    float s = __expf(mrun - mnew);
    float w0 = __expf(a0 - mnew);
    den = den*s + w0;
    #pragma unroll
    for (int i = 0; i < NI; ++i) acc[i] = acc[i]*s + w0*xl0[i];
    mrun = mnew;
  }
  float dinv = 1.0f / fmaxf(den, 1e-16f);
  if constexpr (NI == 8){
    s16x8 o;
    #pragma unroll
    for (int i = 0; i < 8; ++i){
      float v = b[lane*8 + i] + acc[i]*dinv;
      o[i] = f2bf(RELU ? fmaxf(v, 0.f) : v);
    }
    *(s16x8*)((short*)hb + (size_t)n*DOUT + lane*8) = o;
  } else {
    s16x4 o;
    #pragma unroll
    for (int i = 0; i < 4; ++i){
      float v = b[lane*4 + i] + acc[i]*dinv;
      o[i] = f2bf(RELU ? fmaxf(v, 0.f) : v);
    }
    *(s16x4*)((short*)hb + (size_t)n*DOUT + lane*4) = o;
  }
}

// ---------- per-edge bilinear contraction over j (P interleaved: [node x 2cw]) ----------
__global__ void bi_k(const __hip_bfloat16* __restrict__ P, const float* __restrict__ ea,
                     const int* __restrict__ ei, const float* __restrict__ bbi,
                     __hip_bfloat16* __restrict__ bi, int kb, int kcnt){
  int cw = kcnt*ED, w2 = 2*cw;
  int g = blockIdx.x*256 + threadIdx.x;
  if (g >= N_EDGES*kcnt) return;
  int n = g / kcnt, k = g - n*kcnt;
  int src = ei[n], dst = ei[N_EDGES+n];
  const __hip_bfloat16* pl = P + (size_t)src*w2 + k*ED;
  const __hip_bfloat16* pr = P + (size_t)dst*w2 + cw + k*ED;
  const float* eap = ea + (size_t)n*ED;
  float s = 0.f;
  #pragma unroll
  for (int j = 0; j < ED; ++j)
    s += eap[j]*(__bfloat162float(pl[j]) + __bfloat162float(pr[j]));
  int kg = kb + k;
  bi[(size_t)n*KP + kg] = __float2bfloat16(s + bbi[kg]);
}

// ---------- final tiny GEMV + sigmoid ----------
__global__ void out_k(const __hip_bfloat16* __restrict__ m2, const float* __restrict__ Wm3,
                      const float* __restrict__ bm3, float* __restrict__ out){
  int n = blockIdx.x*256 + threadIdx.x;
  if (n >= N_EDGES) return;
  float acc = bm3[0];
  #pragma unroll
  for (int j = 0; j < 32; ++j) acc += __bfloat162float(m2[(size_t)n*128 + j])*Wm3[j];
  out[n] = 1.0f/(1.0f + __expf(-acc));
}

extern "C" void kernel_launch(void* const* d_in, const int* in_sizes, int n_in,
                              void* d_out, int out_size, void* d_ws, size_t ws_size,
                              hipStream_t stream) {
  const float* x   = (const float*)d_in[0];
  const float* ea  = (const float*)d_in[1];
  const int*   ei  = (const int*)d_in[2];
  const float* Wl[4]  = {(const float*)d_in[3],(const float*)d_in[8],(const float*)d_in[13],(const float*)d_in[18]};
  const float* Wr[4]  = {(const float*)d_in[4],(const float*)d_in[9],(const float*)d_in[14],(const float*)d_in[19]};
  const float* We[4]  = {(const float*)d_in[5],(const float*)d_in[10],(const float*)d_in[15],(const float*)d_in[20]};
  const float* att[4] = {(const float*)d_in[6],(const float*)d_in[11],(const float*)d_in[16],(const float*)d_in[21]};
  const float* bia[4] = {(const float*)d_in[7],(const float*)d_in[12],(const float*)d_in[17],(const float*)d_in[22]};
  const float* Wbi = (const float*)d_in[23];
  const float* bbi = (const float*)d_in[24];
  const float* Wm1 = (const float*)d_in[25];
  const float* bm1 = (const float*)d_in[26];
  const float* Wm2 = (const float*)d_in[27];
  const float* bm2 = (const float*)d_in[28];
  const float* Wm3 = (const float*)d_in[29];
  const float* bm3 = (const float*)d_in[30];
  float* out = (float*)d_out;

  char* ws = (char*)d_ws;
  size_t off = 0;
  auto alloc = [&](size_t b){ off = (off + 255) & ~(size_t)255; size_t o = off; off += b; return o; };
  size_t o_bi   = alloc((size_t)M_EDGEP*KP*2);           // 28.90 MB
  size_t o_XLXR = alloc((size_t)M_NODEP*1024*2);         // 20.97 MB
  size_t o_hb   = alloc((size_t)M_NODEP*512*2);          // 10.49 MB
  size_t o_eab  = alloc((size_t)E_AUGP*32*2);            // 3.85 MB
  size_t o_WTa  = alloc((size_t)1327104*2);              // 2.65 MB
  size_t o_WeTa = alloc((size_t)57344*2);
  size_t o_WtA  = alloc((size_t)8704*512*2);             // 8.91 MB
  size_t o_EEP  = alloc((size_t)63000000);               // EE | P-chunk | m1,m2
  size_t o_Wm1T = alloc((size_t)384*KP*2);
  size_t o_Wm2T = alloc((size_t)128*KP*2);
  size_t o_bm1p = alloc(384*4);
  size_t o_bm2p = alloc(128*4);
  size_t o_ma   = alloc((size_t)N_NODES*ED*4);
  size_t o_cnt  = alloc(40000);
  size_t o_rp   = alloc(40004);
  size_t o_fill = alloc(40000);
  size_t o_csr  = alloc(240000);
  if (off > ws_size){
    fprintf(stderr, "kernel_launch: workspace too small: need %zu have %zu\n", off, ws_size);
    return;
  }

  float* meanat = (float*)(ws + o_ma);
  float* cntF   = (float*)(ws + o_cnt);
  int*   rowptr = (int*)(ws + o_rp);
  int*   fill   = (int*)(ws + o_fill);
  int*   csr    = (int*)(ws + o_csr);
  __hip_bfloat16* XLXR = (__hip_bfloat16*)(ws + o_XLXR);
  __hip_bfloat16* hb   = (__hip_bfloat16*)(ws + o_hb);
  __hip_bfloat16* eab  = (__hip_bfloat16*)(ws + o_eab);
  __hip_bfloat16* WTa  = (__hip_bfloat16*)(ws + o_WTa);
  __hip_bfloat16* WeTa = (__hip_bfloat16*)(ws + o_WeTa);
  __hip_bfloat16* WtA  = (__hip_bfloat16*)(ws + o_WtA);
  __half*        EE    = (__half*)(ws + o_EEP);
  __hip_bfloat16* P    = (__hip_bfloat16*)(ws + o_EEP);
  __hip_bfloat16* Wm1T = (__hip_bfloat16*)(ws + o_Wm1T);
  __hip_bfloat16* Wm2T = (__hip_bfloat16*)(ws + o_Wm2T);
  float* bm1p = (float*)(ws + o_bm1p);
  float* bm2p = (float*)(ws + o_bm2p);
  __hip_bfloat16* bi = (__hip_bfloat16*)(ws + o_bi);
  __hip_bfloat16* m1 = (__hip_bfloat16*)(ws + o_EEP);
  __hip_bfloat16* m2 = (__hip_bfloat16*)(ws + o_EEP + 40000000);

  // mean_attr + CSR build
  hipMemsetAsync(ws + o_ma, 0, (o_cnt - o_ma) + 40000, stream);
  hipMemsetAsync(ws + o_fill, 0, 40000, stream);
  edge_attr_sum_k<<<3125, 256, 0, stream>>>(ea, ei, meanat, cntF);
  mean_div_k<<<625, 256, 0, stream>>>(meanat, cntF);
  scan_k<<<1, 1024, 0, stream>>>(cntF, rowptr);
  scatter_k<<<235, 256, 0, stream>>>(ei, rowptr, fill, csr);

  // casts + all weight prep upfront
  cast_h_k<<<(M_NODEP*32 + 255)/256, 256, 0, stream>>>(x, hb, 32);
  cast_ea_k<<<(E_AUGP*32 + 255)/256, 256, 0, stream>>>(ea, meanat, eab);
  prep_weights_k<<<5184, 256, 0, stream>>>(
      Wl[0], Wr[0], We[0], Wl[1], Wr[1], We[1], Wl[2], Wr[2], We[2], Wl[3], Wr[3], We[3],
      Wm1, bm1, Wm2, bm2, WTa, WeTa, Wm1T, Wm2T, bm1p, bm2p);
  wbi_transpose_k<<<(BI_OUT*1024*ED + 255)/256, 256, 0, stream>>>(Wbi, WtA);

  const int dins[4]  = {32, 256, 512, 512};
  const int douts[4] = {256, 512, 512, 512};
  const int wtOff[4] = {0, 16384, 278528, 802816};
  const int weOff[4] = {0, 8192, 24576, 40960};
  for (int L = 0; L < 4; ++L){
    int din = dins[L], dn = douts[L];
    dim3 g1(M_NODEP/256, 2*dn/128);
    mfma_gemm_k<__hip_bfloat16,false,false><<<g1, 256, 0, stream>>>(
        hb, WTa + wtOff[L], XLXR, nullptr, N_NODES, din, din, din, 2*dn);
    dim3 ge(E_AUGP/256, dn/128);
    mfma_gemm_k<__half,false,false><<<ge, 256, 0, stream>>>(
        eab, WeTa + weOff[L], EE, nullptr, E_AUG, 32, 32, 32, dn);
    if (dn == 256)
      gat_fused_k<256,true><<<2500, 256, 0, stream>>>(XLXR, EE, ei, rowptr, csr, att[L], bia[L], hb);
    else if (L == 3)
      gat_fused_k<512,false><<<2500, 256, 0, stream>>>(XLXR, EE, ei, rowptr, csr, att[L], bia[L], hb);
    else
      gat_fused_k<512,true><<<2500, 256, 0, stream>>>(XLXR, EE, ei, rowptr, csr, att[L], bia[L], hb);
  }
  // hb holds final node embeddings [M_NODEP x 512] bf16

  // merged PL|PR GEMM per chunk: N = 2*cw, then bilinear
  const int kbs[3]   = {0, 96, 192};
  const int kcnts[3] = {96, 96, 80};
  const int bases[3] = {0, 3072, 6144};
  for (int c = 0; c < 3; ++c){
    int cw = kcnts[c]*ED, w2 = 2*cw;
    dim3 gp(M_NODEP/256, w2/128);
    mfma_gemm_k<__hip_bfloat16,false,false><<<gp, 256, 0, stream>>>(
        hb, WtA + (size_t)bases[c]*512, P, nullptr, N_NODES, 512, 512, 512, w2);
    bi_k<<<(N_EDGES*kcnts[c] + 255)/256, 256, 0, stream>>>(P, ea, ei, bbi, bi, kbs[c], kcnts[c]);
  }

  dim3 gm1(M_EDGEP/256, 3);
  mfma_gemm_k<__hip_bfloat16,true,true><<<gm1, 256, 0, stream>>>(bi, Wm1T, m1, bm1p, M_EDGEP, KP, KP, KP, 384);
  dim3 gm2(M_EDGEP/256, 1);
  mfma_gemm_k<__hip_bfloat16,true,true><<<gm2, 256, 0, stream>>>(m1, Wm2T, m2, bm2p, M_EDGEP, KP, 384, KP, 128);
  out_k<<<(N_EDGES + 255)/256, 256, 0, stream>>>(m2, Wm3, bm3, out);
}

// Round 9
// 695.613 us; speedup vs baseline: 1.2849x; 1.2849x over previous
//
#include <hip/hip_runtime.h>
#include <hip/hip_bf16.h>
#include <hip/hip_fp16.h>
#include <cstdio>

#define N_NODES 10000
#define M_NODEP 10240            // 80*128
#define N_EDGES 50000
#define M_EDGEP 50176            // 392*128
#define E_AUG   60000
#define E_AUGP  60160            // 470*128
#define ED      16
#define BI_OUT  272
#define KP      288              // 272 padded to 9*32

typedef __attribute__((ext_vector_type(8))) short s16x8;   // 8 bf16 (4 VGPRs)
typedef __attribute__((ext_vector_type(4))) short s16x4;
typedef __attribute__((ext_vector_type(8))) _Float16 h16x8;
typedef __attribute__((ext_vector_type(4))) _Float16 h16x4;
typedef __attribute__((ext_vector_type(4))) float f32x4;

__device__ inline void stc(float* p, float v){ *p = v; }
__device__ inline void stc(__hip_bfloat16* p, float v){ *p = __float2bfloat16(v); }
__device__ inline void stc(__half* p, float v){ *p = __float2half(v); }
__device__ inline float bf2f(short s){ return __uint_as_float(((unsigned)(unsigned short)s) << 16); }
__device__ inline short f2bf(float f){ __hip_bfloat16 h = __float2bfloat16(f); return *(short*)&h; }

// async global->LDS, 16 B per lane; LDS dest is wave-uniform base (lane*16 implicit)
__device__ __forceinline__ void gl2lds16(const void* g, void* l){
  __builtin_amdgcn_global_load_lds((const __attribute__((address_space(1))) void*)g,
                                   (__attribute__((address_space(3))) void*)l, 16, 0, 0);
}

// ---------- mean edge_attr per dst (self-loop fill) ----------
__global__ void edge_attr_sum_k(const float* __restrict__ ea, const int* __restrict__ ei,
                                float* __restrict__ meanat, float* __restrict__ cntF){
  int t = blockIdx.x*256 + threadIdx.x;
  if (t >= N_EDGES*ED) return;
  int e = t >> 4, j = t & 15;
  int dst = ei[N_EDGES + e];
  atomicAdd(&meanat[dst*ED + j], ea[t]);
  if (j == 0) atomicAdd(&cntF[dst], 1.0f);
}

__global__ void mean_div_k(float* __restrict__ meanat, const float* __restrict__ cntF){
  int t = blockIdx.x*256 + threadIdx.x;
  if (t >= N_NODES*ED) return;
  meanat[t] /= fmaxf(cntF[t>>4], 1.0f);
}

// ---------- CSR build ----------
__global__ void scan_k(const float* __restrict__ cntF, int* __restrict__ rowptr){
  __shared__ int s[1024];
  int tid = threadIdx.x;
  int loc[10]; int sum = 0;
  #pragma unroll
  for (int k = 0; k < 10; ++k){
    int i = tid*10 + k;
    int v = (i < N_NODES) ? ((int)cntF[i] + 1) : 0;   // +1 self loop
    loc[k] = sum; sum += v;
  }
  s[tid] = sum; __syncthreads();
  for (int off = 1; off < 1024; off <<= 1){
    int t2 = (tid >= off) ? s[tid-off] : 0;
    __syncthreads();
    s[tid] += t2;
    __syncthreads();
  }
  int pre = s[tid] - sum;
  #pragma unroll
  for (int k = 0; k < 10; ++k){
    int i = tid*10 + k;
    if (i < N_NODES) rowptr[i] = pre + loc[k];
  }
  if (tid == 1023) rowptr[N_NODES] = s[1023];
}

__global__ void scatter_k(const int* __restrict__ ei, const int* __restrict__ rowptr,
                          int* __restrict__ fill, int* __restrict__ csr){
  int e = blockIdx.x*256 + threadIdx.x;
  if (e >= E_AUG) return;
  int dst = (e < N_EDGES) ? ei[N_EDGES+e] : (e - N_EDGES);
  int pos = rowptr[dst] + atomicAdd(&fill[dst], 1);
  csr[pos] = e;
}

// ---------- MFMA bf16 GEMM, 128x128 tile (round-7 verified) ----------
// LDS element offset (row,quad) = row*32 + ((quad+(row>>1))&3)*8 -> 2-way only.
// Staging lane l (rl=l>>2, cq=l&3): chunk l of a 16-row region; global source
// row R+rl, quad (cq-((rl>>1)&3))&3 -> each row one 64B segment (permuted).
template<typename TC, bool BIAS, bool RELU>
__global__ __launch_bounds__(256)
void mfma_gemm_k(const __hip_bfloat16* __restrict__ A, const __hip_bfloat16* __restrict__ Bt,
                 TC* __restrict__ C, const float* __restrict__ bias,
                 int Mstore, int K, int lda, int ldb, int ldc){
  __shared__ __align__(16) __hip_bfloat16 Asm[4096];
  __shared__ __align__(16) __hip_bfloat16 Bsm[4096];
  const int tid = threadIdx.x;
  const int lane = tid & 63, wave = tid >> 6;
  const int wm = (wave >> 1) * 64, wn = (wave & 1) * 64;
  const int m0 = blockIdx.x * 128, n0 = blockIdx.y * 128;
  const int quad = lane >> 4, r16 = lane & 15;

  f32x4 acc[4][4];
  #pragma unroll
  for (int i = 0; i < 4; ++i)
    #pragma unroll
    for (int j = 0; j < 4; ++j)
      acc[i][j] = (f32x4){0.f, 0.f, 0.f, 0.f};

  const int rl = lane >> 2, cq = lane & 3;
  const int row0 = wave*32 + rl;
  const int qg = (cq - ((row0 >> 1) & 3)) & 3;
  const __hip_bfloat16* ga0 = &A[(size_t)(m0 + row0)*lda + qg*8];
  const __hip_bfloat16* ga1 = &A[(size_t)(m0 + row0 + 16)*lda + qg*8];
  const __hip_bfloat16* gb0 = &Bt[(size_t)(n0 + row0)*ldb + qg*8];
  const __hip_bfloat16* gb1 = &Bt[(size_t)(n0 + row0 + 16)*ldb + qg*8];
  __hip_bfloat16* lA0 = &Asm[(wave*32)*32];
  __hip_bfloat16* lA1 = &Asm[(wave*32 + 16)*32];
  __hip_bfloat16* lB0 = &Bsm[(wave*32)*32];
  __hip_bfloat16* lB1 = &Bsm[(wave*32 + 16)*32];

  for (int k0 = 0; k0 < K; k0 += 32){
    gl2lds16(ga0 + k0, lA0);
    gl2lds16(ga1 + k0, lA1);
    gl2lds16(gb0 + k0, lB0);
    gl2lds16(gb1 + k0, lB1);
    __syncthreads();
    s16x8 af[4], bf[4];
    #pragma unroll
    for (int i = 0; i < 4; ++i){
      int row = wm + i*16 + r16;
      af[i] = *(const s16x8*)&Asm[row*32 + (((quad + (row >> 1)) & 3) << 3)];
    }
    #pragma unroll
    for (int j = 0; j < 4; ++j){
      int row = wn + j*16 + r16;
      bf[j] = *(const s16x8*)&Bsm[row*32 + (((quad + (row >> 1)) & 3) << 3)];
    }
    #pragma unroll
    for (int i = 0; i < 4; ++i)
      #pragma unroll
      for (int j = 0; j < 4; ++j)
        acc[i][j] = __builtin_amdgcn_mfma_f32_16x16x32_bf16(af[i], bf[j], acc[i][j], 0, 0, 0);
    __syncthreads();
  }
  #pragma unroll
  for (int i = 0; i < 4; ++i){
    #pragma unroll
    for (int reg = 0; reg < 4; ++reg){
      int gr = m0 + wm + i*16 + quad*4 + reg;
      if (gr >= Mstore) continue;
      #pragma unroll
      for (int j = 0; j < 4; ++j){
        int gc = n0 + wn + j*16 + r16;
        float v = acc[i][j][reg];
        if (BIAS) v += bias[gc];
        if (RELU) v = fmaxf(v, 0.f);
        stc(&C[(size_t)gr*ldc + gc], v);
      }
    }
  }
}

// ---------- fused weight prep: WlWr^T (4 layers), We^T (4), MLP ----------
__global__ void prep_weights_k(
    const float* __restrict__ Wl0, const float* __restrict__ Wr0, const float* __restrict__ We0,
    const float* __restrict__ Wl1, const float* __restrict__ Wr1, const float* __restrict__ We1,
    const float* __restrict__ Wl2, const float* __restrict__ Wr2, const float* __restrict__ We2,
    const float* __restrict__ Wl3, const float* __restrict__ Wr3, const float* __restrict__ We3,
    const float* __restrict__ Wm1, const float* __restrict__ bm1,
    const float* __restrict__ Wm2, const float* __restrict__ bm2,
    __hip_bfloat16* __restrict__ WTa, __hip_bfloat16* __restrict__ WeTa,
    __hip_bfloat16* __restrict__ Wm1T, __hip_bfloat16* __restrict__ Wm2T,
    float* __restrict__ bm1p, float* __restrict__ bm2p){
  int t = blockIdx.x*256 + threadIdx.x;
  if (t < 16384){
    int half = t >> 13, r = t & 8191, i = r >> 8, j = r & 255;
    WTa[(half*256 + j)*32 + i] = __float2bfloat16(half ? Wr0[r] : Wl0[r]);
  } else if (t < 278528){
    int u = t - 16384, half = u >> 17, r = u & 131071, i = r >> 9, j = r & 511;
    WTa[16384 + (half*512 + j)*256 + i] = __float2bfloat16(half ? Wr1[r] : Wl1[r]);
  } else if (t < 802816){
    int u = t - 278528, half = u >> 18, r = u & 262143, i = r >> 9, j = r & 511;
    WTa[278528 + (half*512 + j)*512 + i] = __float2bfloat16(half ? Wr2[r] : Wl2[r]);
  } else if (t < 1327104){
    int u = t - 802816, half = u >> 18, r = u & 262143, i = r >> 9, j = r & 511;
    WTa[802816 + (half*512 + j)*512 + i] = __float2bfloat16(half ? Wr3[r] : Wl3[r]);
  }
  if (t < 8192){
    int n = t >> 5, k = t & 31;
    WeTa[t] = __float2bfloat16((k < 16) ? We0[k*256 + n] : 0.f);
  } else if (t < 24576){
    int u = t - 8192, n = u >> 5, k = u & 31;
    WeTa[t] = __float2bfloat16((k < 16) ? We1[k*512 + n] : 0.f);
  } else if (t < 40960){
    int u = t - 24576, n = u >> 5, k = u & 31;
    WeTa[t] = __float2bfloat16((k < 16) ? We2[k*512 + n] : 0.f);
  } else if (t < 57344){
    int u = t - 40960, n = u >> 5, k = u & 31;
    WeTa[t] = __float2bfloat16((k < 16) ? We3[k*512 + n] : 0.f);
  }
  if (t < 384*KP){
    int n = t / KP, k = t - n*KP;
    Wm1T[t] = __float2bfloat16((n < BI_OUT && k < BI_OUT) ? Wm1[(size_t)k*BI_OUT + n] : 0.f);
  }
  if (t < 128*KP){
    int n = t / KP, k = t - n*KP;
    Wm2T[t] = __float2bfloat16((n < 32 && k < BI_OUT) ? Wm2[(size_t)k*32 + n] : 0.f);
  }
  if (t < 384) bm1p[t] = (t < BI_OUT) ? bm1[t] : 0.f;
  if (t < 128) bm2p[t] = (t < 32) ? bm2[t] : 0.f;
}

__global__ void cast_h_k(const float* __restrict__ h, __hip_bfloat16* __restrict__ hb, int K){
  int t = blockIdx.x*256 + threadIdx.x;
  if (t >= M_NODEP*K) return;
  int r = t / K;
  hb[t] = (r < N_NODES) ? __float2bfloat16(h[t]) : __float2bfloat16(0.f);
}

// ea_aug -> bf16 [E_AUGP x 32] (K padded 16->32)
__global__ void cast_ea_k(const float* __restrict__ ea, const float* __restrict__ meanat,
                          __hip_bfloat16* __restrict__ eab){
  int t = blockIdx.x*256 + threadIdx.x;
  if (t >= E_AUGP*32) return;
  int e = t >> 5, j = t & 31;
  float v = 0.f;
  if (j < 16){
    if (e < N_EDGES) v = ea[(size_t)e*ED + j];
    else if (e < E_AUG) v = meanat[(size_t)(e - N_EDGES)*ED + j];
  }
  eab[t] = __float2bfloat16(v);
}

// Wbi[k<272][i<1024][j<16] -> WtAll: per chunk c, rows base[c]+[0,cw)=L, +[cw,2cw)=R; col = i&511
__global__ void wbi_transpose_k(const float* __restrict__ Wbi, __hip_bfloat16* __restrict__ WtAll){
  int t = blockIdx.x*256 + threadIdx.x;
  if (t >= BI_OUT*1024*ED) return;
  int k = t >> 14, r = t & 16383;
  int i = r >> 4, j = r & 15;
  int c = (k < 96) ? 0 : ((k < 192) ? 1 : 2);
  int kb = c*96;
  int base = c*3072;
  int cw = (c < 2) ? 1536 : 1280;
  int row = base + ((i >= 512) ? cw : 0) + (k - kb)*16 + j;
  WtAll[(size_t)row*512 + (i & 511)] = __float2bfloat16(Wbi[t]);
}

// ---------- fused GAT: one-pass online softmax + aggregate, 1 wave per dst ----------
// d-indexing lane-blocked: d = lane*NI + i; 2-edge unrolled main loop.
template<int DOUT, bool RELU>
__global__ __launch_bounds__(256)
void gat_fused_k(const __hip_bfloat16* __restrict__ XLXR, const __half* __restrict__ EE,
                 const int* __restrict__ ei, const int* __restrict__ rowptr,
                 const int* __restrict__ csr, const float* __restrict__ att,
                 const float* __restrict__ b, __hip_bfloat16* __restrict__ hb){
  constexpr int NI = DOUT/64;
  constexpr int W2 = 2*DOUT;
  int wave = threadIdx.x >> 6, lane = threadIdx.x & 63;
  int n = blockIdx.x*4 + wave;
  if (n >= N_NODES) return;
  int r0 = rowptr[n], r1 = rowptr[n+1];
  int pp = r0 + lane;
  int e_l = 0, s_l = 0;
  if (pp < r1){
    e_l = csr[pp];
    s_l = (e_l < N_EDGES) ? ei[e_l] : (e_l - N_EDGES);
  }
  float xr[NI], at[NI], acc[NI];
  #pragma unroll
  for (int i = 0; i < NI; ++i){
    int d = lane*NI + i;
    xr[i]  = bf2f(((const short*)XLXR)[(size_t)n*W2 + DOUT + d]);
    at[i]  = att[d];
    acc[i] = 0.f;
  }
  float mrun = -1e30f, den = 0.f;
  int p = r0;
  for (; p + 1 < r1; p += 2){
    int i0 = p - r0, i1 = i0 + 1;
    int e0, s0, e1, s1;
    if (i1 < 64){
      e0 = __shfl(e_l, i0, 64); s0 = __shfl(s_l, i0, 64);
      e1 = __shfl(e_l, i1, 64); s1 = __shfl(s_l, i1, 64);
    } else {
      if (i0 < 64){ e0 = __shfl(e_l, i0, 64); s0 = __shfl(s_l, i0, 64); }
      else { e0 = csr[p]; s0 = (e0 < N_EDGES) ? ei[e0] : (e0 - N_EDGES); }
      e1 = csr[p+1]; s1 = (e1 < N_EDGES) ? ei[e1] : (e1 - N_EDGES);
    }
    const short* xp0 = (const short*)XLXR + (size_t)s0*W2 + lane*NI;
    const short* xp1 = (const short*)XLXR + (size_t)s1*W2 + lane*NI;
    const _Float16* ep0 = (const _Float16*)EE + (size_t)e0*DOUT + lane*NI;
    const _Float16* ep1 = (const _Float16*)EE + (size_t)e1*DOUT + lane*NI;
    float xl0[NI], xl1[NI];
    float a0 = 0.f, a1 = 0.f;
    if constexpr (NI == 8){
      s16x8 xv0 = *(const s16x8*)xp0; h16x8 ev0 = *(const h16x8*)ep0;
      s16x8 xv1 = *(const s16x8*)xp1; h16x8 ev1 = *(const h16x8*)ep1;
      #pragma unroll
      for (int i = 0; i < 8; ++i){
        xl0[i] = bf2f(xv0[i]); xl1[i] = bf2f(xv1[i]);
        float v0 = xl0[i] + xr[i] + (float)ev0[i];
        float v1 = xl1[i] + xr[i] + (float)ev1[i];
        v0 = (v0 > 0.f) ? v0 : 0.2f*v0;
        v1 = (v1 > 0.f) ? v1 : 0.2f*v1;
        a0 += at[i]*v0; a1 += at[i]*v1;
      }
    } else {
      s16x4 xv0 = *(const s16x4*)xp0; h16x4 ev0 = *(const h16x4*)ep0;
      s16x4 xv1 = *(const s16x4*)xp1; h16x4 ev1 = *(const h16x4*)ep1;
      #pragma unroll
      for (int i = 0; i < 4; ++i){
        xl0[i] = bf2f(xv0[i]); xl1[i] = bf2f(xv1[i]);
        float v0 = xl0[i] + xr[i] + (float)ev0[i];
        float v1 = xl1[i] + xr[i] + (float)ev1[i];
        v0 = (v0 > 0.f) ? v0 : 0.2f*v0;
        v1 = (v1 > 0.f) ? v1 : 0.2f*v1;
        a0 += at[i]*v0; a1 += at[i]*v1;
      }
    }
    #pragma unroll
    for (int off = 32; off; off >>= 1){
      a0 += __shfl_xor(a0, off, 64);
      a1 += __shfl_xor(a1, off, 64);
    }
    float mnew = fmaxf(mrun, fmaxf(a0, a1));
    float s = __expf(mrun - mnew);
    float w0 = __expf(a0 - mnew);
    float w1 = __expf(a1 - mnew);
    den = den*s + w0 + w1;
    #pragma unroll
    for (int i = 0; i < NI; ++i) acc[i] = acc[i]*s + w0*xl0[i] + w1*xl1[i];
    mrun = mnew;
  }
  if (p < r1){
    int i0 = p - r0;
    int e0, s0;
    if (i0 < 64){ e0 = __shfl(e_l, i0, 64); s0 = __shfl(s_l, i0, 64); }
    else { e0 = csr[p]; s0 = (e0 < N_EDGES) ? ei[e0] : (e0 - N_EDGES); }
    const short* xp0 = (const short*)XLXR + (size_t)s0*W2 + lane*NI;
    const _Float16* ep0 = (const _Float16*)EE + (size_t)e0*DOUT + lane*NI;
    float xl0[NI];
    float a0 = 0.f;
    #pragma unroll
    for (int i = 0; i < NI; ++i){
      xl0[i] = bf2f(xp0[i]);
      float v0 = xl0[i] + xr[i] + (float)ep0[i];
      v0 = (v0 > 0.f) ? v0 : 0.2f*v0;
      a0 += at[i]*v0;
    }
    #pragma unroll
    for (int off = 32; off; off >>= 1) a0 += __shfl_xor(a0, off, 64);
    float mnew = fmaxf(mrun, a0);
    float s = __expf(mrun - mnew);
    float w0 = __expf(a0 - mnew);
    den = den*s + w0;
    #pragma unroll
    for (int i = 0; i < NI; ++i) acc[i] = acc[i]*s + w0*xl0[i];
    mrun = mnew;
  }
  float dinv = 1.0f / fmaxf(den, 1e-16f);
  if constexpr (NI == 8){
    s16x8 o;
    #pragma unroll
    for (int i = 0; i < 8; ++i){
      float v = b[lane*8 + i] + acc[i]*dinv;
      o[i] = f2bf(RELU ? fmaxf(v, 0.f) : v);
    }
    *(s16x8*)((short*)hb + (size_t)n*DOUT + lane*8) = o;
  } else {
    s16x4 o;
    #pragma unroll
    for (int i = 0; i < 4; ++i){
      float v = b[lane*4 + i] + acc[i]*dinv;
      o[i] = f2bf(RELU ? fmaxf(v, 0.f) : v);
    }
    *(s16x4*)((short*)hb + (size_t)n*DOUT + lane*4) = o;
  }
}

// ---------- per-edge bilinear contraction over j (P interleaved: [node x 2cw]) ----------
__global__ void bi_k(const __hip_bfloat16* __restrict__ P, const float* __restrict__ ea,
                     const int* __restrict__ ei, const float* __restrict__ bbi,
                     __hip_bfloat16* __restrict__ bi, int kb, int kcnt){
  int cw = kcnt*ED, w2 = 2*cw;
  int g = blockIdx.x*256 + threadIdx.x;
  if (g >= N_EDGES*kcnt) return;
  int n = g / kcnt, k = g - n*kcnt;
  int src = ei[n], dst = ei[N_EDGES+n];
  const __hip_bfloat16* pl = P + (size_t)src*w2 + k*ED;
  const __hip_bfloat16* pr = P + (size_t)dst*w2 + cw + k*ED;
  const float* eap = ea + (size_t)n*ED;
  float s = 0.f;
  #pragma unroll
  for (int j = 0; j < ED; ++j)
    s += eap[j]*(__bfloat162float(pl[j]) + __bfloat162float(pr[j]));
  int kg = kb + k;
  bi[(size_t)n*KP + kg] = __float2bfloat16(s + bbi[kg]);
}

// ---------- final tiny GEMV + sigmoid ----------
__global__ void out_k(const __hip_bfloat16* __restrict__ m2, const float* __restrict__ Wm3,
                      const float* __restrict__ bm3, float* __restrict__ out){
  int n = blockIdx.x*256 + threadIdx.x;
  if (n >= N_EDGES) return;
  float acc = bm3[0];
  #pragma unroll
  for (int j = 0; j < 32; ++j) acc += __bfloat162float(m2[(size_t)n*128 + j])*Wm3[j];
  out[n] = 1.0f/(1.0f + __expf(-acc));
}

extern "C" void kernel_launch(void* const* d_in, const int* in_sizes, int n_in,
                              void* d_out, int out_size, void* d_ws, size_t ws_size,
                              hipStream_t stream) {
  const float* x   = (const float*)d_in[0];
  const float* ea  = (const float*)d_in[1];
  const int*   ei  = (const int*)d_in[2];
  const float* Wl[4]  = {(const float*)d_in[3],(const float*)d_in[8],(const float*)d_in[13],(const float*)d_in[18]};
  const float* Wr[4]  = {(const float*)d_in[4],(const float*)d_in[9],(const float*)d_in[14],(const float*)d_in[19]};
  const float* We[4]  = {(const float*)d_in[5],(const float*)d_in[10],(const float*)d_in[15],(const float*)d_in[20]};
  const float* att[4] = {(const float*)d_in[6],(const float*)d_in[11],(const float*)d_in[16],(const float*)d_in[21]};
  const float* bia[4] = {(const float*)d_in[7],(const float*)d_in[12],(const float*)d_in[17],(const float*)d_in[22]};
  const float* Wbi = (const float*)d_in[23];
  const float* bbi = (const float*)d_in[24];
  const float* Wm1 = (const float*)d_in[25];
  const float* bm1 = (const float*)d_in[26];
  const float* Wm2 = (const float*)d_in[27];
  const float* bm2 = (const float*)d_in[28];
  const float* Wm3 = (const float*)d_in[29];
  const float* bm3 = (const float*)d_in[30];
  float* out = (float*)d_out;

  char* ws = (char*)d_ws;
  size_t off = 0;
  auto alloc = [&](size_t b){ off = (off + 255) & ~(size_t)255; size_t o = off; off += b; return o; };
  size_t o_bi   = alloc((size_t)M_EDGEP*KP*2);           // 28.90 MB
  size_t o_XLXR = alloc((size_t)M_NODEP*1024*2);         // 20.97 MB
  size_t o_hb   = alloc((size_t)M_NODEP*512*2);          // 10.49 MB
  size_t o_eab  = alloc((size_t)E_AUGP*32*2);            // 3.85 MB
  size_t o_WTa  = alloc((size_t)1327104*2);              // 2.65 MB
  size_t o_WeTa = alloc((size_t)57344*2);
  size_t o_WtA  = alloc((size_t)8704*512*2);             // 8.91 MB
  size_t o_EEP  = alloc((size_t)63000000);               // EE | P-chunk | m1,m2
  size_t o_Wm1T = alloc((size_t)384*KP*2);
  size_t o_Wm2T = alloc((size_t)128*KP*2);
  size_t o_bm1p = alloc(384*4);
  size_t o_bm2p = alloc(128*4);
  size_t o_ma   = alloc((size_t)N_NODES*ED*4);
  size_t o_cnt  = alloc(40000);
  size_t o_rp   = alloc(40004);
  size_t o_fill = alloc(40000);
  size_t o_csr  = alloc(240000);
  if (off > ws_size){
    fprintf(stderr, "kernel_launch: workspace too small: need %zu have %zu\n", off, ws_size);
    return;
  }

  float* meanat = (float*)(ws + o_ma);
  float* cntF   = (float*)(ws + o_cnt);
  int*   rowptr = (int*)(ws + o_rp);
  int*   fill   = (int*)(ws + o_fill);
  int*   csr    = (int*)(ws + o_csr);
  __hip_bfloat16* XLXR = (__hip_bfloat16*)(ws + o_XLXR);
  __hip_bfloat16* hb   = (__hip_bfloat16*)(ws + o_hb);
  __hip_bfloat16* eab  = (__hip_bfloat16*)(ws + o_eab);
  __hip_bfloat16* WTa  = (__hip_bfloat16*)(ws + o_WTa);
  __hip_bfloat16* WeTa = (__hip_bfloat16*)(ws + o_WeTa);
  __hip_bfloat16* WtA  = (__hip_bfloat16*)(ws + o_WtA);
  __half*        EE    = (__half*)(ws + o_EEP);
  __hip_bfloat16* P    = (__hip_bfloat16*)(ws + o_EEP);
  __hip_bfloat16* Wm1T = (__hip_bfloat16*)(ws + o_Wm1T);
  __hip_bfloat16* Wm2T = (__hip_bfloat16*)(ws + o_Wm2T);
  float* bm1p = (float*)(ws + o_bm1p);
  float* bm2p = (float*)(ws + o_bm2p);
  __hip_bfloat16* bi = (__hip_bfloat16*)(ws + o_bi);
  __hip_bfloat16* m1 = (__hip_bfloat16*)(ws + o_EEP);
  __hip_bfloat16* m2 = (__hip_bfloat16*)(ws + o_EEP + 40000000);

  // mean_attr + CSR build
  hipMemsetAsync(ws + o_ma, 0, (o_cnt - o_ma) + 40000, stream);
  hipMemsetAsync(ws + o_fill, 0, 40000, stream);
  edge_attr_sum_k<<<3125, 256, 0, stream>>>(ea, ei, meanat, cntF);
  mean_div_k<<<625, 256, 0, stream>>>(meanat, cntF);
  scan_k<<<1, 1024, 0, stream>>>(cntF, rowptr);
  scatter_k<<<235, 256, 0, stream>>>(ei, rowptr, fill, csr);

  // casts + all weight prep upfront
  cast_h_k<<<(M_NODEP*32 + 255)/256, 256, 0, stream>>>(x, hb, 32);
  cast_ea_k<<<(E_AUGP*32 + 255)/256, 256, 0, stream>>>(ea, meanat, eab);
  prep_weights_k<<<5184, 256, 0, stream>>>(
      Wl[0], Wr[0], We[0], Wl[1], Wr[1], We[1], Wl[2], Wr[2], We[2], Wl[3], Wr[3], We[3],
      Wm1, bm1, Wm2, bm2, WTa, WeTa, Wm1T, Wm2T, bm1p, bm2p);
  wbi_transpose_k<<<(BI_OUT*1024*ED + 255)/256, 256, 0, stream>>>(Wbi, WtA);

  const int dins[4]  = {32, 256, 512, 512};
  const int douts[4] = {256, 512, 512, 512};
  const int wtOff[4] = {0, 16384, 278528, 802816};
  const int weOff[4] = {0, 8192, 24576, 40960};
  for (int L = 0; L < 4; ++L){
    int din = dins[L], dn = douts[L];
    dim3 g1(M_NODEP/128, 2*dn/128);
    mfma_gemm_k<__hip_bfloat16,false,false><<<g1, 256, 0, stream>>>(
        hb, WTa + wtOff[L], XLXR, nullptr, N_NODES, din, din, din, 2*dn);
    dim3 ge(E_AUGP/128, dn/128);
    mfma_gemm_k<__half,false,false><<<ge, 256, 0, stream>>>(
        eab, WeTa + weOff[L], EE, nullptr, E_AUG, 32, 32, 32, dn);
    if (dn == 256)
      gat_fused_k<256,true><<<2500, 256, 0, stream>>>(XLXR, EE, ei, rowptr, csr, att[L], bia[L], hb);
    else if (L == 3)
      gat_fused_k<512,false><<<2500, 256, 0, stream>>>(XLXR, EE, ei, rowptr, csr, att[L], bia[L], hb);
    else
      gat_fused_k<512,true><<<2500, 256, 0, stream>>>(XLXR, EE, ei, rowptr, csr, att[L], bia[L], hb);
  }
  // hb holds final node embeddings [M_NODEP x 512] bf16

  // merged PL|PR GEMM per chunk: N = 2*cw, then bilinear
  const int kbs[3]   = {0, 96, 192};
  const int kcnts[3] = {96, 96, 80};
  const int bases[3] = {0, 3072, 6144};
  for (int c = 0; c < 3; ++c){
    int cw = kcnts[c]*ED, w2 = 2*cw;
    dim3 gp(M_NODEP/128, w2/128);
    mfma_gemm_k<__hip_bfloat16,false,false><<<gp, 256, 0, stream>>>(
        hb, WtA + (size_t)bases[c]*512, P, nullptr, N_NODES, 512, 512, 512, w2);
    bi_k<<<(N_EDGES*kcnts[c] + 255)/256, 256, 0, stream>>>(P, ea, ei, bbi, bi, kbs[c], kcnts[c]);
  }

  dim3 gm1(M_EDGEP/128, 3);
  mfma_gemm_k<__hip_bfloat16,true,true><<<gm1, 256, 0, stream>>>(bi, Wm1T, m1, bm1p, M_EDGEP, KP, KP, KP, 384);
  dim3 gm2(M_EDGEP/128, 1);
  mfma_gemm_k<__hip_bfloat16,true,true><<<gm2, 256, 0, stream>>>(m1, Wm2T, m2, bm2p, M_EDGEP, KP, 384, KP, 128);
  out_k<<<(N_EDGES + 255)/256, 256, 0, stream>>>(m2, Wm3, bm3, out);
}

// Round 10
// 657.823 us; speedup vs baseline: 1.3588x; 1.0574x over previous
//
#include <hip/hip_runtime.h>
#include <hip/hip_bf16.h>
#include <hip/hip_fp16.h>
#include <cstdio>

#define N_NODES 10000
#define M_NODEP 10240            // 80*128
#define N_EDGES 50000
#define M_EDGEP 50176            // 392*128
#define E_AUG   60000
#define E_AUGP  60160            // 470*128
#define ED      16
#define BI_OUT  272
#define KP      288              // 272 padded to 9*32

typedef __attribute__((ext_vector_type(8))) short s16x8;   // 8 bf16 (4 VGPRs)
typedef __attribute__((ext_vector_type(4))) short s16x4;
typedef __attribute__((ext_vector_type(8))) _Float16 h16x8;
typedef __attribute__((ext_vector_type(4))) _Float16 h16x4;
typedef __attribute__((ext_vector_type(4))) float f32x4;

__device__ inline void stc(float* p, float v){ *p = v; }
__device__ inline void stc(__hip_bfloat16* p, float v){ *p = __float2bfloat16(v); }
__device__ inline void stc(__half* p, float v){ *p = __float2half(v); }
__device__ inline float bf2f(short s){ return __uint_as_float(((unsigned)(unsigned short)s) << 16); }
__device__ inline short f2bf(float f){ __hip_bfloat16 h = __float2bfloat16(f); return *(short*)&h; }

// async global->LDS, 16 B per lane; LDS dest is wave-uniform base (lane*16 implicit)
__device__ __forceinline__ void gl2lds16(const void* g, void* l){
  __builtin_amdgcn_global_load_lds((const __attribute__((address_space(1))) void*)g,
                                   (__attribute__((address_space(3))) void*)l, 16, 0, 0);
}

// B pre-swizzle index: logical B^T element (row n, col k) of a matrix with
// kSteps = K/32  ->  element offset ((nb*kSteps + s)*8 + f)*512 + lane*8 + ii
// where nb=n>>7, f=(n>>4)&7, r=n&15, s=k>>5, q=(k>>3)&3, ii=k&7, lane=q*16+r.
// GEMM reads frag f at step s as one coalesced 1KB segment (lane*16B).
__device__ inline size_t preidx(int n, int k, int kSteps){
  int nb = n >> 7, f = (n >> 4) & 7, r = n & 15;
  int s = k >> 5, q = (k >> 3) & 3, ii = k & 7;
  return ((((size_t)nb*kSteps + s)*8 + f)*64 + q*16 + r)*8 + ii;
}

// ---------- mean edge_attr per dst (self-loop fill) ----------
__global__ void edge_attr_sum_k(const float* __restrict__ ea, const int* __restrict__ ei,
                                float* __restrict__ meanat, float* __restrict__ cntF){
  int t = blockIdx.x*256 + threadIdx.x;
  if (t >= N_EDGES*ED) return;
  int e = t >> 4, j = t & 15;
  int dst = ei[N_EDGES + e];
  atomicAdd(&meanat[dst*ED + j], ea[t]);
  if (j == 0) atomicAdd(&cntF[dst], 1.0f);
}

__global__ void mean_div_k(float* __restrict__ meanat, const float* __restrict__ cntF){
  int t = blockIdx.x*256 + threadIdx.x;
  if (t >= N_NODES*ED) return;
  meanat[t] /= fmaxf(cntF[t>>4], 1.0f);
}

// ---------- CSR build ----------
__global__ void scan_k(const float* __restrict__ cntF, int* __restrict__ rowptr){
  __shared__ int s[1024];
  int tid = threadIdx.x;
  int loc[10]; int sum = 0;
  #pragma unroll
  for (int k = 0; k < 10; ++k){
    int i = tid*10 + k;
    int v = (i < N_NODES) ? ((int)cntF[i] + 1) : 0;   // +1 self loop
    loc[k] = sum; sum += v;
  }
  s[tid] = sum; __syncthreads();
  for (int off = 1; off < 1024; off <<= 1){
    int t2 = (tid >= off) ? s[tid-off] : 0;
    __syncthreads();
    s[tid] += t2;
    __syncthreads();
  }
  int pre = s[tid] - sum;
  #pragma unroll
  for (int k = 0; k < 10; ++k){
    int i = tid*10 + k;
    if (i < N_NODES) rowptr[i] = pre + loc[k];
  }
  if (tid == 1023) rowptr[N_NODES] = s[1023];
}

__global__ void scatter_k(const int* __restrict__ ei, const int* __restrict__ rowptr,
                          int* __restrict__ fill, int* __restrict__ csr){
  int e = blockIdx.x*256 + threadIdx.x;
  if (e >= E_AUG) return;
  int dst = (e < N_EDGES) ? ei[N_EDGES+e] : (e - N_EDGES);
  int pos = rowptr[dst] + atomicAdd(&fill[dst], 1);
  csr[pos] = e;
}

// ---------- MFMA bf16 GEMM, 128x128 tile, B from pre-swizzled global ----------
// A: LDS double-buffer, single barrier per k-iter; XOR-quad swizzle (r7-verified):
// LDS elem (row,quad) = row*32 + ((quad+(row>>1))&3)*8; staging lane l supplies
// row R+l/4, quad ((l&3)-((row>>1)&3))&3 -> rows are 64B global segments.
// B: fragment-order layout (see preidx), 4 x 1KB coalesced loads per k-step,
// prefetched one step ahead (no barrier dependency).
template<typename TC, bool BIAS, bool RELU>
__global__ __launch_bounds__(256)
void mfma_gemm_k(const __hip_bfloat16* __restrict__ A, const __hip_bfloat16* __restrict__ Bp,
                 TC* __restrict__ C, const float* __restrict__ bias,
                 int Mstore, int K, int lda, int ldc){
  __shared__ __align__(16) __hip_bfloat16 Asm[2][4096];
  const int tid = threadIdx.x;
  const int lane = tid & 63, wave = tid >> 6;
  const int wm = (wave >> 1) * 64, wn = (wave & 1) * 64;
  const int m0 = blockIdx.x * 128, n0 = blockIdx.y * 128;
  const int quad = lane >> 4, r16 = lane & 15;
  const int kSteps = K >> 5;

  f32x4 acc[4][4];
  #pragma unroll
  for (int i = 0; i < 4; ++i)
    #pragma unroll
    for (int j = 0; j < 4; ++j)
      acc[i][j] = (f32x4){0.f, 0.f, 0.f, 0.f};

  const int rl = lane >> 2, cq = lane & 3;
  const int row0 = wave*32 + rl;
  const int qg = (cq - ((row0 >> 1) & 3)) & 3;
  const __hip_bfloat16* ga0 = &A[(size_t)(m0 + row0)*lda + qg*8];
  const __hip_bfloat16* ga1 = &A[(size_t)(m0 + row0 + 16)*lda + qg*8];
  const int aoff0 = (wave*32)*32, aoff1 = (wave*32 + 16)*32;

  // B fragment base: frags f = wn/16 + j, each 512 elements (64 lanes x 8)
  const __hip_bfloat16* gB = Bp + (((size_t)blockIdx.y*kSteps)*8 + (wn >> 4))*512 + (size_t)lane*8;

  // prologue: stage A step 0, load B step 0
  gl2lds16(ga0, &Asm[0][aoff0]);
  gl2lds16(ga1, &Asm[0][aoff1]);
  s16x8 bcur[4], bnxt[4];
  #pragma unroll
  for (int j = 0; j < 4; ++j) bcur[j] = *(const s16x8*)(gB + j*512);

  for (int s = 0; s < kSteps; ++s){
    __syncthreads();                       // drains A stage (and B prefetch) for step s
    if (s + 1 < kSteps){
      int k0 = (s + 1) * 32;
      gl2lds16(ga0 + k0, &Asm[(s+1)&1][aoff0]);
      gl2lds16(ga1 + k0, &Asm[(s+1)&1][aoff1]);
      const __hip_bfloat16* gBn = gB + (size_t)(s+1)*4096;
      #pragma unroll
      for (int j = 0; j < 4; ++j) bnxt[j] = *(const s16x8*)(gBn + j*512);
    }
    s16x8 af[4];
    #pragma unroll
    for (int i = 0; i < 4; ++i){
      int row = wm + i*16 + r16;
      af[i] = *(const s16x8*)&Asm[s & 1][row*32 + (((quad + (row >> 1)) & 3) << 3)];
    }
    #pragma unroll
    for (int i = 0; i < 4; ++i)
      #pragma unroll
      for (int j = 0; j < 4; ++j)
        acc[i][j] = __builtin_amdgcn_mfma_f32_16x16x32_bf16(af[i], bcur[j], acc[i][j], 0, 0, 0);
    #pragma unroll
    for (int j = 0; j < 4; ++j) bcur[j] = bnxt[j];
  }
  #pragma unroll
  for (int i = 0; i < 4; ++i){
    #pragma unroll
    for (int reg = 0; reg < 4; ++reg){
      int gr = m0 + wm + i*16 + quad*4 + reg;
      if (gr >= Mstore) continue;
      #pragma unroll
      for (int j = 0; j < 4; ++j){
        int gc = n0 + wn + j*16 + r16;
        float v = acc[i][j][reg];
        if (BIAS) v += bias[gc];
        if (RELU) v = fmaxf(v, 0.f);
        stc(&C[(size_t)gr*ldc + gc], v);
      }
    }
  }
}

// ---------- fused weight prep (pre-swizzled B layouts) ----------
// WTa elem offsets: L0 0 (512x32), L1 16384 (1024x256), L2 278528 (1024x512), L3 802816
// WeTa: L0 0 (256x32), L1 8192 (512x32), L2 24576, L3 40960
__global__ void prep_weights_k(
    const float* __restrict__ Wl0, const float* __restrict__ Wr0, const float* __restrict__ We0,
    const float* __restrict__ Wl1, const float* __restrict__ Wr1, const float* __restrict__ We1,
    const float* __restrict__ Wl2, const float* __restrict__ Wr2, const float* __restrict__ We2,
    const float* __restrict__ Wl3, const float* __restrict__ Wr3, const float* __restrict__ We3,
    const float* __restrict__ Wm1, const float* __restrict__ bm1,
    const float* __restrict__ Wm2, const float* __restrict__ bm2,
    __hip_bfloat16* __restrict__ WTa, __hip_bfloat16* __restrict__ WeTa,
    __hip_bfloat16* __restrict__ Wm1T, __hip_bfloat16* __restrict__ Wm2T,
    float* __restrict__ bm1p, float* __restrict__ bm2p){
  int t = blockIdx.x*256 + threadIdx.x;
  if (t < 16384){
    int half = t >> 13, r = t & 8191, i = r >> 8, j = r & 255;       // Wl0/Wr0 [32x256]
    WTa[preidx(half*256 + j, i, 1)] = __float2bfloat16(half ? Wr0[r] : Wl0[r]);
  } else if (t < 278528){
    int u = t - 16384, half = u >> 17, r = u & 131071, i = r >> 9, j = r & 511;
    WTa[16384 + preidx(half*512 + j, i, 8)] = __float2bfloat16(half ? Wr1[r] : Wl1[r]);
  } else if (t < 802816){
    int u = t - 278528, half = u >> 18, r = u & 262143, i = r >> 9, j = r & 511;
    WTa[278528 + preidx(half*512 + j, i, 16)] = __float2bfloat16(half ? Wr2[r] : Wl2[r]);
  } else if (t < 1327104){
    int u = t - 802816, half = u >> 18, r = u & 262143, i = r >> 9, j = r & 511;
    WTa[802816 + preidx(half*512 + j, i, 16)] = __float2bfloat16(half ? Wr3[r] : Wl3[r]);
  }
  if (t < 8192){
    int n = t >> 5, k = t & 31;
    WeTa[preidx(n, k, 1)] = __float2bfloat16((k < 16) ? We0[k*256 + n] : 0.f);
  } else if (t < 24576){
    int u = t - 8192, n = u >> 5, k = u & 31;
    WeTa[8192 + preidx(n, k, 1)] = __float2bfloat16((k < 16) ? We1[k*512 + n] : 0.f);
  } else if (t < 40960){
    int u = t - 24576, n = u >> 5, k = u & 31;
    WeTa[24576 + preidx(n, k, 1)] = __float2bfloat16((k < 16) ? We2[k*512 + n] : 0.f);
  } else if (t < 57344){
    int u = t - 40960, n = u >> 5, k = u & 31;
    WeTa[40960 + preidx(n, k, 1)] = __float2bfloat16((k < 16) ? We3[k*512 + n] : 0.f);
  }
  if (t < 384*KP){
    int n = t / KP, k = t - n*KP;
    Wm1T[preidx(n, k, 9)] = __float2bfloat16((n < BI_OUT && k < BI_OUT) ? Wm1[(size_t)k*BI_OUT + n] : 0.f);
  }
  if (t < 128*KP){
    int n = t / KP, k = t - n*KP;
    Wm2T[preidx(n, k, 9)] = __float2bfloat16((n < 32 && k < BI_OUT) ? Wm2[(size_t)k*32 + n] : 0.f);
  }
  if (t < 384) bm1p[t] = (t < BI_OUT) ? bm1[t] : 0.f;
  if (t < 128) bm2p[t] = (t < 32) ? bm2[t] : 0.f;
}

__global__ void cast_h_k(const float* __restrict__ h, __hip_bfloat16* __restrict__ hb, int K){
  int t = blockIdx.x*256 + threadIdx.x;
  if (t >= M_NODEP*K) return;
  int r = t / K;
  hb[t] = (r < N_NODES) ? __float2bfloat16(h[t]) : __float2bfloat16(0.f);
}

// ea_aug -> bf16 [E_AUGP x 32] (K padded 16->32)
__global__ void cast_ea_k(const float* __restrict__ ea, const float* __restrict__ meanat,
                          __hip_bfloat16* __restrict__ eab){
  int t = blockIdx.x*256 + threadIdx.x;
  if (t >= E_AUGP*32) return;
  int e = t >> 5, j = t & 31;
  float v = 0.f;
  if (j < 16){
    if (e < N_EDGES) v = ea[(size_t)e*ED + j];
    else if (e < E_AUG) v = meanat[(size_t)(e - N_EDGES)*ED + j];
  }
  eab[t] = __float2bfloat16(v);
}

// Wbi[k<272][i<1024][j<16] -> WtAll: per chunk c (rows 2cw x 512, pre-swizzled, kSteps=16)
__global__ void wbi_transpose_k(const float* __restrict__ Wbi, __hip_bfloat16* __restrict__ WtAll){
  int t = blockIdx.x*256 + threadIdx.x;
  if (t >= BI_OUT*1024*ED) return;
  int k = t >> 14, r = t & 16383;
  int i = r >> 4, j = r & 15;
  int c = (k < 96) ? 0 : ((k < 192) ? 1 : 2);
  int kb = c*96;
  int cw = (c < 2) ? 1536 : 1280;
  size_t baseE = (size_t)c * 1572864;          // chunk elem base: 0, 3072*512, 2*3072*512
  int row = ((i >= 512) ? cw : 0) + (k - kb)*16 + j;
  WtAll[baseE + preidx(row, i & 511, 16)] = __float2bfloat16(Wbi[t]);
}

// ---------- fused GAT: one-pass online softmax + aggregate, 1 wave per dst ----------
// d-indexing lane-blocked: d = lane*NI + i; 2-edge unrolled main loop.
template<int DOUT, bool RELU>
__global__ __launch_bounds__(256)
void gat_fused_k(const __hip_bfloat16* __restrict__ XLXR, const __half* __restrict__ EE,
                 const int* __restrict__ ei, const int* __restrict__ rowptr,
                 const int* __restrict__ csr, const float* __restrict__ att,
                 const float* __restrict__ b, __hip_bfloat16* __restrict__ hb){
  constexpr int NI = DOUT/64;
  constexpr int W2 = 2*DOUT;
  int wave = threadIdx.x >> 6, lane = threadIdx.x & 63;
  int n = blockIdx.x*4 + wave;
  if (n >= N_NODES) return;
  int r0 = rowptr[n], r1 = rowptr[n+1];
  int pp = r0 + lane;
  int e_l = 0, s_l = 0;
  if (pp < r1){
    e_l = csr[pp];
    s_l = (e_l < N_EDGES) ? ei[e_l] : (e_l - N_EDGES);
  }
  float xr[NI], at[NI], acc[NI];
  #pragma unroll
  for (int i = 0; i < NI; ++i){
    int d = lane*NI + i;
    xr[i]  = bf2f(((const short*)XLXR)[(size_t)n*W2 + DOUT + d]);
    at[i]  = att[d];
    acc[i] = 0.f;
  }
  float mrun = -1e30f, den = 0.f;
  int p = r0;
  for (; p + 1 < r1; p += 2){
    int i0 = p - r0, i1 = i0 + 1;
    int e0, s0, e1, s1;
    if (i1 < 64){
      e0 = __shfl(e_l, i0, 64); s0 = __shfl(s_l, i0, 64);
      e1 = __shfl(e_l, i1, 64); s1 = __shfl(s_l, i1, 64);
    } else {
      if (i0 < 64){ e0 = __shfl(e_l, i0, 64); s0 = __shfl(s_l, i0, 64); }
      else { e0 = csr[p]; s0 = (e0 < N_EDGES) ? ei[e0] : (e0 - N_EDGES); }
      e1 = csr[p+1]; s1 = (e1 < N_EDGES) ? ei[e1] : (e1 - N_EDGES);
    }
    const short* xp0 = (const short*)XLXR + (size_t)s0*W2 + lane*NI;
    const short* xp1 = (const short*)XLXR + (size_t)s1*W2 + lane*NI;
    const _Float16* ep0 = (const _Float16*)EE + (size_t)e0*DOUT + lane*NI;
    const _Float16* ep1 = (const _Float16*)EE + (size_t)e1*DOUT + lane*NI;
    float xl0[NI], xl1[NI];
    float a0 = 0.f, a1 = 0.f;
    if constexpr (NI == 8){
      s16x8 xv0 = *(const s16x8*)xp0; h16x8 ev0 = *(const h16x8*)ep0;
      s16x8 xv1 = *(const s16x8*)xp1; h16x8 ev1 = *(const h16x8*)ep1;
      #pragma unroll
      for (int i = 0; i < 8; ++i){
        xl0[i] = bf2f(xv0[i]); xl1[i] = bf2f(xv1[i]);
        float v0 = xl0[i] + xr[i] + (float)ev0[i];
        float v1 = xl1[i] + xr[i] + (float)ev1[i];
        v0 = (v0 > 0.f) ? v0 : 0.2f*v0;
        v1 = (v1 > 0.f) ? v1 : 0.2f*v1;
        a0 += at[i]*v0; a1 += at[i]*v1;
      }
    } else {
      s16x4 xv0 = *(const s16x4*)xp0; h16x4 ev0 = *(const h16x4*)ep0;
      s16x4 xv1 = *(const s16x4*)xp1; h16x4 ev1 = *(const h16x4*)ep1;
      #pragma unroll
      for (int i = 0; i < 4; ++i){
        xl0[i] = bf2f(xv0[i]); xl1[i] = bf2f(xv1[i]);
        float v0 = xl0[i] + xr[i] + (float)ev0[i];
        float v1 = xl1[i] + xr[i] + (float)ev1[i];
        v0 = (v0 > 0.f) ? v0 : 0.2f*v0;
        v1 = (v1 > 0.f) ? v1 : 0.2f*v1;
        a0 += at[i]*v0; a1 += at[i]*v1;
      }
    }
    #pragma unroll
    for (int off = 32; off; off >>= 1){
      a0 += __shfl_xor(a0, off, 64);
      a1 += __shfl_xor(a1, off, 64);
    }
    float mnew = fmaxf(mrun, fmaxf(a0, a1));
    float s = __expf(mrun - mnew);
    float w0 = __expf(a0 - mnew);
    float w1 = __expf(a1 - mnew);
    den = den*s + w0 + w1;
    #pragma unroll
    for (int i = 0; i < NI; ++i) acc[i] = acc[i]*s + w0*xl0[i] + w1*xl1[i];
    mrun = mnew;
  }
  if (p < r1){
    int i0 = p - r0;
    int e0, s0;
    if (i0 < 64){ e0 = __shfl(e_l, i0, 64); s0 = __shfl(s_l, i0, 64); }
    else { e0 = csr[p]; s0 = (e0 < N_EDGES) ? ei[e0] : (e0 - N_EDGES); }
    const short* xp0 = (const short*)XLXR + (size_t)s0*W2 + lane*NI;
    const _Float16* ep0 = (const _Float16*)EE + (size_t)e0*DOUT + lane*NI;
    float xl0[NI];
    float a0 = 0.f;
    #pragma unroll
    for (int i = 0; i < NI; ++i){
      xl0[i] = bf2f(xp0[i]);
      float v0 = xl0[i] + xr[i] + (float)ep0[i];
      v0 = (v0 > 0.f) ? v0 : 0.2f*v0;
      a0 += at[i]*v0;
    }
    #pragma unroll
    for (int off = 32; off; off >>= 1) a0 += __shfl_xor(a0, off, 64);
    float mnew = fmaxf(mrun, a0);
    float s = __expf(mrun - mnew);
    float w0 = __expf(a0 - mnew);
    den = den*s + w0;
    #pragma unroll
    for (int i = 0; i < NI; ++i) acc[i] = acc[i]*s + w0*xl0[i];
    mrun = mnew;
  }
  float dinv = 1.0f / fmaxf(den, 1e-16f);
  if constexpr (NI == 8){
    s16x8 o;
    #pragma unroll
    for (int i = 0; i < 8; ++i){
      float v = b[lane*8 + i] + acc[i]*dinv;
      o[i] = f2bf(RELU ? fmaxf(v, 0.f) : v);
    }
    *(s16x8*)((short*)hb + (size_t)n*DOUT + lane*8) = o;
  } else {
    s16x4 o;
    #pragma unroll
    for (int i = 0; i < 4; ++i){
      float v = b[lane*4 + i] + acc[i]*dinv;
      o[i] = f2bf(RELU ? fmaxf(v, 0.f) : v);
    }
    *(s16x4*)((short*)hb + (size_t)n*DOUT + lane*4) = o;
  }
}

// ---------- per-edge bilinear contraction over j (P interleaved: [node x 2cw]) ----------
__global__ void bi_k(const __hip_bfloat16* __restrict__ P, const float* __restrict__ ea,
                     const int* __restrict__ ei, const float* __restrict__ bbi,
                     __hip_bfloat16* __restrict__ bi, int kb, int kcnt){
  int cw = kcnt*ED, w2 = 2*cw;
  int g = blockIdx.x*256 + threadIdx.x;
  if (g >= N_EDGES*kcnt) return;
  int n = g / kcnt, k = g - n*kcnt;
  int src = ei[n], dst = ei[N_EDGES+n];
  const __hip_bfloat16* pl = P + (size_t)src*w2 + k*ED;
  const __hip_bfloat16* pr = P + (size_t)dst*w2 + cw + k*ED;
  const float* eap = ea + (size_t)n*ED;
  float s = 0.f;
  #pragma unroll
  for (int j = 0; j < ED; ++j)
    s += eap[j]*(__bfloat162float(pl[j]) + __bfloat162float(pr[j]));
  int kg = kb + k;
  bi[(size_t)n*KP + kg] = __float2bfloat16(s + bbi[kg]);
}

// ---------- final tiny GEMV + sigmoid ----------
__global__ void out_k(const __hip_bfloat16* __restrict__ m2, const float* __restrict__ Wm3,
                      const float* __restrict__ bm3, float* __restrict__ out){
  int n = blockIdx.x*256 + threadIdx.x;
  if (n >= N_EDGES) return;
  float acc = bm3[0];
  #pragma unroll
  for (int j = 0; j < 32; ++j) acc += __bfloat162float(m2[(size_t)n*128 + j])*Wm3[j];
  out[n] = 1.0f/(1.0f + __expf(-acc));
}

extern "C" void kernel_launch(void* const* d_in, const int* in_sizes, int n_in,
                              void* d_out, int out_size, void* d_ws, size_t ws_size,
                              hipStream_t stream) {
  const float* x   = (const float*)d_in[0];
  const float* ea  = (const float*)d_in[1];
  const int*   ei  = (const int*)d_in[2];
  const float* Wl[4]  = {(const float*)d_in[3],(const float*)d_in[8],(const float*)d_in[13],(const float*)d_in[18]};
  const float* Wr[4]  = {(const float*)d_in[4],(const float*)d_in[9],(const float*)d_in[14],(const float*)d_in[19]};
  const float* We[4]  = {(const float*)d_in[5],(const float*)d_in[10],(const float*)d_in[15],(const float*)d_in[20]};
  const float* att[4] = {(const float*)d_in[6],(const float*)d_in[11],(const float*)d_in[16],(const float*)d_in[21]};
  const float* bia[4] = {(const float*)d_in[7],(const float*)d_in[12],(const float*)d_in[17],(const float*)d_in[22]};
  const float* Wbi = (const float*)d_in[23];
  const float* bbi = (const float*)d_in[24];
  const float* Wm1 = (const float*)d_in[25];
  const float* bm1 = (const float*)d_in[26];
  const float* Wm2 = (const float*)d_in[27];
  const float* bm2 = (const float*)d_in[28];
  const float* Wm3 = (const float*)d_in[29];
  const float* bm3 = (const float*)d_in[30];
  float* out = (float*)d_out;

  char* ws = (char*)d_ws;
  size_t off = 0;
  auto alloc = [&](size_t b){ off = (off + 255) & ~(size_t)255; size_t o = off; off += b; return o; };
  size_t o_bi   = alloc((size_t)M_EDGEP*KP*2);           // 28.90 MB
  size_t o_XLXR = alloc((size_t)M_NODEP*1024*2);         // 20.97 MB
  size_t o_hb   = alloc((size_t)M_NODEP*512*2);          // 10.49 MB
  size_t o_eab  = alloc((size_t)E_AUGP*32*2);            // 3.85 MB
  size_t o_WTa  = alloc((size_t)1327104*2);              // 2.65 MB
  size_t o_WeTa = alloc((size_t)57344*2);
  size_t o_WtA  = alloc((size_t)8704*512*2);             // 8.91 MB
  size_t o_EEP  = alloc((size_t)63000000);               // EE | P-chunk | m1,m2
  size_t o_Wm1T = alloc((size_t)384*KP*2);
  size_t o_Wm2T = alloc((size_t)128*KP*2);
  size_t o_bm1p = alloc(384*4);
  size_t o_bm2p = alloc(128*4);
  size_t o_ma   = alloc((size_t)N_NODES*ED*4);
  size_t o_cnt  = alloc(40000);
  size_t o_rp   = alloc(40004);
  size_t o_fill = alloc(40000);
  size_t o_csr  = alloc(240000);
  if (off > ws_size){
    fprintf(stderr, "kernel_launch: workspace too small: need %zu have %zu\n", off, ws_size);
    return;
  }

  float* meanat = (float*)(ws + o_ma);
  float* cntF   = (float*)(ws + o_cnt);
  int*   rowptr = (int*)(ws + o_rp);
  int*   fill   = (int*)(ws + o_fill);
  int*   csr    = (int*)(ws + o_csr);
  __hip_bfloat16* XLXR = (__hip_bfloat16*)(ws + o_XLXR);
  __hip_bfloat16* hb   = (__hip_bfloat16*)(ws + o_hb);
  __hip_bfloat16* eab  = (__hip_bfloat16*)(ws + o_eab);
  __hip_bfloat16* WTa  = (__hip_bfloat16*)(ws + o_WTa);
  __hip_bfloat16* WeTa = (__hip_bfloat16*)(ws + o_WeTa);
  __hip_bfloat16* WtA  = (__hip_bfloat16*)(ws + o_WtA);
  __half*        EE    = (__half*)(ws + o_EEP);
  __hip_bfloat16* P    = (__hip_bfloat16*)(ws + o_EEP);
  __hip_bfloat16* Wm1T = (__hip_bfloat16*)(ws + o_Wm1T);
  __hip_bfloat16* Wm2T = (__hip_bfloat16*)(ws + o_Wm2T);
  float* bm1p = (float*)(ws + o_bm1p);
  float* bm2p = (float*)(ws + o_bm2p);
  __hip_bfloat16* bi = (__hip_bfloat16*)(ws + o_bi);
  __hip_bfloat16* m1 = (__hip_bfloat16*)(ws + o_EEP);
  __hip_bfloat16* m2 = (__hip_bfloat16*)(ws + o_EEP + 40000000);

  // mean_attr + CSR build
  hipMemsetAsync(ws + o_ma, 0, (o_cnt - o_ma) + 40000, stream);
  hipMemsetAsync(ws + o_fill, 0, 40000, stream);
  edge_attr_sum_k<<<3125, 256, 0, stream>>>(ea, ei, meanat, cntF);
  mean_div_k<<<625, 256, 0, stream>>>(meanat, cntF);
  scan_k<<<1, 1024, 0, stream>>>(cntF, rowptr);
  scatter_k<<<235, 256, 0, stream>>>(ei, rowptr, fill, csr);

  // casts + all weight prep upfront
  cast_h_k<<<(M_NODEP*32 + 255)/256, 256, 0, stream>>>(x, hb, 32);
  cast_ea_k<<<(E_AUGP*32 + 255)/256, 256, 0, stream>>>(ea, meanat, eab);
  prep_weights_k<<<5184, 256, 0, stream>>>(
      Wl[0], Wr[0], We[0], Wl[1], Wr[1], We[1], Wl[2], Wr[2], We[2], Wl[3], Wr[3], We[3],
      Wm1, bm1, Wm2, bm2, WTa, WeTa, Wm1T, Wm2T, bm1p, bm2p);
  wbi_transpose_k<<<(BI_OUT*1024*ED + 255)/256, 256, 0, stream>>>(Wbi, WtA);

  const int dins[4]  = {32, 256, 512, 512};
  const int douts[4] = {256, 512, 512, 512};
  const int wtOff[4] = {0, 16384, 278528, 802816};
  const int weOff[4] = {0, 8192, 24576, 40960};
  for (int L = 0; L < 4; ++L){
    int din = dins[L], dn = douts[L];
    dim3 g1(M_NODEP/128, 2*dn/128);
    mfma_gemm_k<__hip_bfloat16,false,false><<<g1, 256, 0, stream>>>(
        hb, WTa + wtOff[L], XLXR, nullptr, N_NODES, din, din, 2*dn);
    dim3 ge(E_AUGP/128, dn/128);
    mfma_gemm_k<__half,false,false><<<ge, 256, 0, stream>>>(
        eab, WeTa + weOff[L], EE, nullptr, E_AUG, 32, 32, dn);
    if (dn == 256)
      gat_fused_k<256,true><<<2500, 256, 0, stream>>>(XLXR, EE, ei, rowptr, csr, att[L], bia[L], hb);
    else if (L == 3)
      gat_fused_k<512,false><<<2500, 256, 0, stream>>>(XLXR, EE, ei, rowptr, csr, att[L], bia[L], hb);
    else
      gat_fused_k<512,true><<<2500, 256, 0, stream>>>(XLXR, EE, ei, rowptr, csr, att[L], bia[L], hb);
  }
  // hb holds final node embeddings [M_NODEP x 512] bf16

  // merged PL|PR GEMM per chunk: N = 2*cw, then bilinear
  const int kbs[3]      = {0, 96, 192};
  const int kcnts[3]    = {96, 96, 80};
  const size_t baseE[3] = {0, 1572864, 3145728};   // chunk elem offsets in WtA
  for (int c = 0; c < 3; ++c){
    int cw = kcnts[c]*ED, w2 = 2*cw;
    dim3 gp(M_NODEP/128, w2/128);
    mfma_gemm_k<__hip_bfloat16,false,false><<<gp, 256, 0, stream>>>(
        hb, WtA + baseE[c], P, nullptr, N_NODES, 512, 512, w2);
    bi_k<<<(N_EDGES*kcnts[c] + 255)/256, 256, 0, stream>>>(P, ea, ei, bbi, bi, kbs[c], kcnts[c]);
  }

  dim3 gm1(M_EDGEP/128, 3);
  mfma_gemm_k<__hip_bfloat16,true,true><<<gm1, 256, 0, stream>>>(bi, Wm1T, m1, bm1p, M_EDGEP, KP, KP, 384);
  dim3 gm2(M_EDGEP/128, 1);
  mfma_gemm_k<__hip_bfloat16,true,true><<<gm2, 256, 0, stream>>>(m1, Wm2T, m2, bm2p, M_EDGEP, KP, 384, 128);
  out_k<<<(N_EDGES + 255)/256, 256, 0, stream>>>(m2, Wm3, bm3, out);
}

// Round 11
// 639.301 us; speedup vs baseline: 1.3981x; 1.0290x over previous
//
#include <hip/hip_runtime.h>
#include <hip/hip_bf16.h>
#include <hip/hip_fp16.h>
#include <cstdio>

#define N_NODES 10000
#define M_NODEP 10240            // 80*128
#define N_EDGES 50000
#define M_EDGEP 50176            // 392*128
#define E_AUG   60000
#define E_AUGP  60160            // 470*128
#define ED      16
#define BI_OUT  272
#define KP      288              // 272 padded to 9*32

typedef __attribute__((ext_vector_type(8))) short s16x8;   // 8 bf16 (4 VGPRs)
typedef __attribute__((ext_vector_type(4))) short s16x4;
typedef __attribute__((ext_vector_type(8))) _Float16 h16x8;
typedef __attribute__((ext_vector_type(4))) _Float16 h16x4;
typedef __attribute__((ext_vector_type(4))) float f32x4;

__device__ inline void stc(float* p, float v){ *p = v; }
__device__ inline void stc(__hip_bfloat16* p, float v){ *p = __float2bfloat16(v); }
__device__ inline void stc(__half* p, float v){ *p = __float2half(v); }
__device__ inline float bf2f(short s){ return __uint_as_float(((unsigned)(unsigned short)s) << 16); }
__device__ inline short f2bf(float f){ __hip_bfloat16 h = __float2bfloat16(f); return *(short*)&h; }

// async global->LDS, 16 B per lane; LDS dest is wave-uniform base (lane*16 implicit)
__device__ __forceinline__ void gl2lds16(const void* g, void* l){
  __builtin_amdgcn_global_load_lds((const __attribute__((address_space(1))) void*)g,
                                   (__attribute__((address_space(3))) void*)l, 16, 0, 0);
}

// B pre-swizzle index: logical B^T element (row n, col k) of a matrix with
// kSteps = K/32  ->  element offset ((nb*kSteps + s)*8 + f)*512 + lane*8 + ii
// where nb=n>>7, f=(n>>4)&7, r=n&15, s=k>>5, q=(k>>3)&3, ii=k&7, lane=q*16+r.
__device__ inline size_t preidx(int n, int k, int kSteps){
  int nb = n >> 7, f = (n >> 4) & 7, r = n & 15;
  int s = k >> 5, q = (k >> 3) & 3, ii = k & 7;
  return ((((size_t)nb*kSteps + s)*8 + f)*64 + q*16 + r)*8 + ii;
}

// ---------- mean edge_attr per dst (self-loop fill) ----------
__global__ void edge_attr_sum_k(const float* __restrict__ ea, const int* __restrict__ ei,
                                float* __restrict__ meanat, float* __restrict__ cntF){
  int t = blockIdx.x*256 + threadIdx.x;
  if (t >= N_EDGES*ED) return;
  int e = t >> 4, j = t & 15;
  int dst = ei[N_EDGES + e];
  atomicAdd(&meanat[dst*ED + j], ea[t]);
  if (j == 0) atomicAdd(&cntF[dst], 1.0f);
}

__global__ void mean_div_k(float* __restrict__ meanat, const float* __restrict__ cntF){
  int t = blockIdx.x*256 + threadIdx.x;
  if (t >= N_NODES*ED) return;
  meanat[t] /= fmaxf(cntF[t>>4], 1.0f);
}

// ---------- CSR build ----------
__global__ void scan_k(const float* __restrict__ cntF, int* __restrict__ rowptr){
  __shared__ int s[1024];
  int tid = threadIdx.x;
  int loc[10]; int sum = 0;
  #pragma unroll
  for (int k = 0; k < 10; ++k){
    int i = tid*10 + k;
    int v = (i < N_NODES) ? ((int)cntF[i] + 1) : 0;   // +1 self loop
    loc[k] = sum; sum += v;
  }
  s[tid] = sum; __syncthreads();
  for (int off = 1; off < 1024; off <<= 1){
    int t2 = (tid >= off) ? s[tid-off] : 0;
    __syncthreads();
    s[tid] += t2;
    __syncthreads();
  }
  int pre = s[tid] - sum;
  #pragma unroll
  for (int k = 0; k < 10; ++k){
    int i = tid*10 + k;
    if (i < N_NODES) rowptr[i] = pre + loc[k];
  }
  if (tid == 1023) rowptr[N_NODES] = s[1023];
}

__global__ void scatter_k(const int* __restrict__ ei, const int* __restrict__ rowptr,
                          int* __restrict__ fill, int* __restrict__ csr){
  int e = blockIdx.x*256 + threadIdx.x;
  if (e >= E_AUG) return;
  int dst = (e < N_EDGES) ? ei[N_EDGES+e] : (e - N_EDGES);
  int pos = rowptr[dst] + atomicAdd(&fill[dst], 1);
  csr[pos] = e;
}

// ---------- MFMA bf16 GEMM, 128x128 tile, B from pre-swizzled global ----------
// A: LDS double-buffer, single barrier per k-iter; XOR-quad swizzle (r7-verified).
// B: fragment-order layout (preidx), 4 x 1KB coalesced loads per k-step,
// prefetched one step ahead (no barrier dependency).
template<typename TC, bool BIAS, bool RELU>
__global__ __launch_bounds__(256)
void mfma_gemm_k(const __hip_bfloat16* __restrict__ A, const __hip_bfloat16* __restrict__ Bp,
                 TC* __restrict__ C, const float* __restrict__ bias,
                 int Mstore, int K, int lda, int ldc){
  __shared__ __align__(16) __hip_bfloat16 Asm[2][4096];
  const int tid = threadIdx.x;
  const int lane = tid & 63, wave = tid >> 6;
  const int wm = (wave >> 1) * 64, wn = (wave & 1) * 64;
  const int m0 = blockIdx.x * 128, n0 = blockIdx.y * 128;
  const int quad = lane >> 4, r16 = lane & 15;
  const int kSteps = K >> 5;

  f32x4 acc[4][4];
  #pragma unroll
  for (int i = 0; i < 4; ++i)
    #pragma unroll
    for (int j = 0; j < 4; ++j)
      acc[i][j] = (f32x4){0.f, 0.f, 0.f, 0.f};

  const int rl = lane >> 2, cq = lane & 3;
  const int row0 = wave*32 + rl;
  const int qg = (cq - ((row0 >> 1) & 3)) & 3;
  const __hip_bfloat16* ga0 = &A[(size_t)(m0 + row0)*lda + qg*8];
  const __hip_bfloat16* ga1 = &A[(size_t)(m0 + row0 + 16)*lda + qg*8];
  const int aoff0 = (wave*32)*32, aoff1 = (wave*32 + 16)*32;

  const __hip_bfloat16* gB = Bp + (((size_t)blockIdx.y*kSteps)*8 + (wn >> 4))*512 + (size_t)lane*8;

  gl2lds16(ga0, &Asm[0][aoff0]);
  gl2lds16(ga1, &Asm[0][aoff1]);
  s16x8 bcur[4], bnxt[4];
  #pragma unroll
  for (int j = 0; j < 4; ++j) bcur[j] = *(const s16x8*)(gB + j*512);

  for (int s = 0; s < kSteps; ++s){
    __syncthreads();
    if (s + 1 < kSteps){
      int k0 = (s + 1) * 32;
      gl2lds16(ga0 + k0, &Asm[(s+1)&1][aoff0]);
      gl2lds16(ga1 + k0, &Asm[(s+1)&1][aoff1]);
      const __hip_bfloat16* gBn = gB + (size_t)(s+1)*4096;
      #pragma unroll
      for (int j = 0; j < 4; ++j) bnxt[j] = *(const s16x8*)(gBn + j*512);
    }
    s16x8 af[4];
    #pragma unroll
    for (int i = 0; i < 4; ++i){
      int row = wm + i*16 + r16;
      af[i] = *(const s16x8*)&Asm[s & 1][row*32 + (((quad + (row >> 1)) & 3) << 3)];
    }
    #pragma unroll
    for (int i = 0; i < 4; ++i)
      #pragma unroll
      for (int j = 0; j < 4; ++j)
        acc[i][j] = __builtin_amdgcn_mfma_f32_16x16x32_bf16(af[i], bcur[j], acc[i][j], 0, 0, 0);
    #pragma unroll
    for (int j = 0; j < 4; ++j) bcur[j] = bnxt[j];
  }
  #pragma unroll
  for (int i = 0; i < 4; ++i){
    #pragma unroll
    for (int reg = 0; reg < 4; ++reg){
      int gr = m0 + wm + i*16 + quad*4 + reg;
      if (gr >= Mstore) continue;
      #pragma unroll
      for (int j = 0; j < 4; ++j){
        int gc = n0 + wn + j*16 + r16;
        float v = acc[i][j][reg];
        if (BIAS) v += bias[gc];
        if (RELU) v = fmaxf(v, 0.f);
        stc(&C[(size_t)gr*ldc + gc], v);
      }
    }
  }
}

// ---------- fused weight prep (pre-swizzled B layouts) ----------
__global__ void prep_weights_k(
    const float* __restrict__ Wl0, const float* __restrict__ Wr0, const float* __restrict__ We0,
    const float* __restrict__ Wl1, const float* __restrict__ Wr1, const float* __restrict__ We1,
    const float* __restrict__ Wl2, const float* __restrict__ Wr2, const float* __restrict__ We2,
    const float* __restrict__ Wl3, const float* __restrict__ Wr3, const float* __restrict__ We3,
    const float* __restrict__ Wm1, const float* __restrict__ bm1,
    const float* __restrict__ Wm2, const float* __restrict__ bm2,
    __hip_bfloat16* __restrict__ WTa, __hip_bfloat16* __restrict__ WeTa,
    __hip_bfloat16* __restrict__ Wm1T, __hip_bfloat16* __restrict__ Wm2T,
    float* __restrict__ bm1p, float* __restrict__ bm2p){
  int t = blockIdx.x*256 + threadIdx.x;
  if (t < 16384){
    int half = t >> 13, r = t & 8191, i = r >> 8, j = r & 255;       // Wl0/Wr0 [32x256]
    WTa[preidx(half*256 + j, i, 1)] = __float2bfloat16(half ? Wr0[r] : Wl0[r]);
  } else if (t < 278528){
    int u = t - 16384, half = u >> 17, r = u & 131071, i = r >> 9, j = r & 511;
    WTa[16384 + preidx(half*512 + j, i, 8)] = __float2bfloat16(half ? Wr1[r] : Wl1[r]);
  } else if (t < 802816){
    int u = t - 278528, half = u >> 18, r = u & 262143, i = r >> 9, j = r & 511;
    WTa[278528 + preidx(half*512 + j, i, 16)] = __float2bfloat16(half ? Wr2[r] : Wl2[r]);
  } else if (t < 1327104){
    int u = t - 802816, half = u >> 18, r = u & 262143, i = r >> 9, j = r & 511;
    WTa[802816 + preidx(half*512 + j, i, 16)] = __float2bfloat16(half ? Wr3[r] : Wl3[r]);
  }
  if (t < 8192){
    int n = t >> 5, k = t & 31;
    WeTa[preidx(n, k, 1)] = __float2bfloat16((k < 16) ? We0[k*256 + n] : 0.f);
  } else if (t < 24576){
    int u = t - 8192, n = u >> 5, k = u & 31;
    WeTa[8192 + preidx(n, k, 1)] = __float2bfloat16((k < 16) ? We1[k*512 + n] : 0.f);
  } else if (t < 40960){
    int u = t - 24576, n = u >> 5, k = u & 31;
    WeTa[24576 + preidx(n, k, 1)] = __float2bfloat16((k < 16) ? We2[k*512 + n] : 0.f);
  } else if (t < 57344){
    int u = t - 40960, n = u >> 5, k = u & 31;
    WeTa[40960 + preidx(n, k, 1)] = __float2bfloat16((k < 16) ? We3[k*512 + n] : 0.f);
  }
  if (t < 384*KP){
    int n = t / KP, k = t - n*KP;
    Wm1T[preidx(n, k, 9)] = __float2bfloat16((n < BI_OUT && k < BI_OUT) ? Wm1[(size_t)k*BI_OUT + n] : 0.f);
  }
  if (t < 128*KP){
    int n = t / KP, k = t - n*KP;
    Wm2T[preidx(n, k, 9)] = __float2bfloat16((n < 32 && k < BI_OUT) ? Wm2[(size_t)k*32 + n] : 0.f);
  }
  if (t < 384) bm1p[t] = (t < BI_OUT) ? bm1[t] : 0.f;
  if (t < 128) bm2p[t] = (t < 32) ? bm2[t] : 0.f;
}

__global__ void cast_h_k(const float* __restrict__ h, __hip_bfloat16* __restrict__ hb, int K){
  int t = blockIdx.x*256 + threadIdx.x;
  if (t >= M_NODEP*K) return;
  int r = t / K;
  hb[t] = (r < N_NODES) ? __float2bfloat16(h[t]) : __float2bfloat16(0.f);
}

// ea_aug -> bf16 [E_AUGP x 32] (K padded 16->32)
__global__ void cast_ea_k(const float* __restrict__ ea, const float* __restrict__ meanat,
                          __hip_bfloat16* __restrict__ eab){
  int t = blockIdx.x*256 + threadIdx.x;
  if (t >= E_AUGP*32) return;
  int e = t >> 5, j = t & 31;
  float v = 0.f;
  if (j < 16){
    if (e < N_EDGES) v = ea[(size_t)e*ED + j];
    else if (e < E_AUG) v = meanat[(size_t)(e - N_EDGES)*ED + j];
  }
  eab[t] = __float2bfloat16(v);
}

// Wbi[k<272][i<1024][j<16] -> WtAll: 2 chunks, each rows [0,cw)=L, [cw,2cw)=R; col=i&511
__global__ void wbi_transpose_k(const float* __restrict__ Wbi, __hip_bfloat16* __restrict__ WtAll){
  int t = blockIdx.x*256 + threadIdx.x;
  if (t >= BI_OUT*1024*ED) return;
  int k = t >> 14, r = t & 16383;
  int i = r >> 4, j = r & 15;
  int c = (k < 136) ? 0 : 1;
  int kb = c*136;
  const int cw = 2176;                         // 136*16
  size_t baseE = (size_t)c * 2228224;          // 4352*512
  int row = ((i >= 512) ? cw : 0) + (k - kb)*16 + j;
  WtAll[baseE + preidx(row, i & 511, 16)] = __float2bfloat16(Wbi[t]);
}

// ---------- fused GAT: one-pass online softmax + aggregate, 1 wave per dst ----------
template<int DOUT, bool RELU>
__global__ __launch_bounds__(256)
void gat_fused_k(const __hip_bfloat16* __restrict__ XLXR, const __half* __restrict__ EE,
                 const int* __restrict__ ei, const int* __restrict__ rowptr,
                 const int* __restrict__ csr, const float* __restrict__ att,
                 const float* __restrict__ b, __hip_bfloat16* __restrict__ hb){
  constexpr int NI = DOUT/64;
  constexpr int W2 = 2*DOUT;
  int wave = threadIdx.x >> 6, lane = threadIdx.x & 63;
  int n = blockIdx.x*4 + wave;
  if (n >= N_NODES) return;
  int r0 = rowptr[n], r1 = rowptr[n+1];
  int pp = r0 + lane;
  int e_l = 0, s_l = 0;
  if (pp < r1){
    e_l = csr[pp];
    s_l = (e_l < N_EDGES) ? ei[e_l] : (e_l - N_EDGES);
  }
  float xr[NI], at[NI], acc[NI];
  #pragma unroll
  for (int i = 0; i < NI; ++i){
    int d = lane*NI + i;
    xr[i]  = bf2f(((const short*)XLXR)[(size_t)n*W2 + DOUT + d]);
    at[i]  = att[d];
    acc[i] = 0.f;
  }
  float mrun = -1e30f, den = 0.f;
  int p = r0;
  for (; p + 1 < r1; p += 2){
    int i0 = p - r0, i1 = i0 + 1;
    int e0, s0, e1, s1;
    if (i1 < 64){
      e0 = __shfl(e_l, i0, 64); s0 = __shfl(s_l, i0, 64);
      e1 = __shfl(e_l, i1, 64); s1 = __shfl(s_l, i1, 64);
    } else {
      if (i0 < 64){ e0 = __shfl(e_l, i0, 64); s0 = __shfl(s_l, i0, 64); }
      else { e0 = csr[p]; s0 = (e0 < N_EDGES) ? ei[e0] : (e0 - N_EDGES); }
      e1 = csr[p+1]; s1 = (e1 < N_EDGES) ? ei[e1] : (e1 - N_EDGES);
    }
    const short* xp0 = (const short*)XLXR + (size_t)s0*W2 + lane*NI;
    const short* xp1 = (const short*)XLXR + (size_t)s1*W2 + lane*NI;
    const _Float16* ep0 = (const _Float16*)EE + (size_t)e0*DOUT + lane*NI;
    const _Float16* ep1 = (const _Float16*)EE + (size_t)e1*DOUT + lane*NI;
    float xl0[NI], xl1[NI];
    float a0 = 0.f, a1 = 0.f;
    if constexpr (NI == 8){
      s16x8 xv0 = *(const s16x8*)xp0; h16x8 ev0 = *(const h16x8*)ep0;
      s16x8 xv1 = *(const s16x8*)xp1; h16x8 ev1 = *(const h16x8*)ep1;
      #pragma unroll
      for (int i = 0; i < 8; ++i){
        xl0[i] = bf2f(xv0[i]); xl1[i] = bf2f(xv1[i]);
        float v0 = xl0[i] + xr[i] + (float)ev0[i];
        float v1 = xl1[i] + xr[i] + (float)ev1[i];
        v0 = (v0 > 0.f) ? v0 : 0.2f*v0;
        v1 = (v1 > 0.f) ? v1 : 0.2f*v1;
        a0 += at[i]*v0; a1 += at[i]*v1;
      }
    } else {
      s16x4 xv0 = *(const s16x4*)xp0; h16x4 ev0 = *(const h16x4*)ep0;
      s16x4 xv1 = *(const s16x4*)xp1; h16x4 ev1 = *(const h16x4*)ep1;
      #pragma unroll
      for (int i = 0; i < 4; ++i){
        xl0[i] = bf2f(xv0[i]); xl1[i] = bf2f(xv1[i]);
        float v0 = xl0[i] + xr[i] + (float)ev0[i];
        float v1 = xl1[i] + xr[i] + (float)ev1[i];
        v0 = (v0 > 0.f) ? v0 : 0.2f*v0;
        v1 = (v1 > 0.f) ? v1 : 0.2f*v1;
        a0 += at[i]*v0; a1 += at[i]*v1;
      }
    }
    #pragma unroll
    for (int off = 32; off; off >>= 1){
      a0 += __shfl_xor(a0, off, 64);
      a1 += __shfl_xor(a1, off, 64);
    }
    float mnew = fmaxf(mrun, fmaxf(a0, a1));
    float s = __expf(mrun - mnew);
    float w0 = __expf(a0 - mnew);
    float w1 = __expf(a1 - mnew);
    den = den*s + w0 + w1;
    #pragma unroll
    for (int i = 0; i < NI; ++i) acc[i] = acc[i]*s + w0*xl0[i] + w1*xl1[i];
    mrun = mnew;
  }
  if (p < r1){
    int i0 = p - r0;
    int e0, s0;
    if (i0 < 64){ e0 = __shfl(e_l, i0, 64); s0 = __shfl(s_l, i0, 64); }
    else { e0 = csr[p]; s0 = (e0 < N_EDGES) ? ei[e0] : (e0 - N_EDGES); }
    const short* xp0 = (const short*)XLXR + (size_t)s0*W2 + lane*NI;
    const _Float16* ep0 = (const _Float16*)EE + (size_t)e0*DOUT + lane*NI;
    float xl0[NI];
    float a0 = 0.f;
    #pragma unroll
    for (int i = 0; i < NI; ++i){
      xl0[i] = bf2f(xp0[i]);
      float v0 = xl0[i] + xr[i] + (float)ep0[i];
      v0 = (v0 > 0.f) ? v0 : 0.2f*v0;
      a0 += at[i]*v0;
    }
    #pragma unroll
    for (int off = 32; off; off >>= 1) a0 += __shfl_xor(a0, off, 64);
    float mnew = fmaxf(mrun, a0);
    float s = __expf(mrun - mnew);
    float w0 = __expf(a0 - mnew);
    den = den*s + w0;
    #pragma unroll
    for (int i = 0; i < NI; ++i) acc[i] = acc[i]*s + w0*xl0[i];
    mrun = mnew;
  }
  float dinv = 1.0f / fmaxf(den, 1e-16f);
  if constexpr (NI == 8){
    s16x8 o;
    #pragma unroll
    for (int i = 0; i < 8; ++i){
      float v = b[lane*8 + i] + acc[i]*dinv;
      o[i] = f2bf(RELU ? fmaxf(v, 0.f) : v);
    }
    *(s16x8*)((short*)hb + (size_t)n*DOUT + lane*8) = o;
  } else {
    s16x4 o;
    #pragma unroll
    for (int i = 0; i < 4; ++i){
      float v = b[lane*4 + i] + acc[i]*dinv;
      o[i] = f2bf(RELU ? fmaxf(v, 0.f) : v);
    }
    *(s16x4*)((short*)hb + (size_t)n*DOUT + lane*4) = o;
  }
}

// ---------- per-edge bilinear, dst-ordered via CSR (PR rows L1/L2-hot) ----------
__global__ void bi_k(const __hip_bfloat16* __restrict__ P, const float* __restrict__ ea,
                     const int* __restrict__ ei, const int* __restrict__ csr,
                     const float* __restrict__ bbi, __hip_bfloat16* __restrict__ bi,
                     int kb, int kcnt){
  int cw = kcnt*ED, w2 = 2*cw;
  int g = blockIdx.x*256 + threadIdx.x;
  if (g >= E_AUG*kcnt) return;
  int p = g / kcnt, k = g - p*kcnt;
  int e = csr[p];
  if (e >= N_EDGES) return;                    // self-loop pseudo-edge: no bi output
  int src = ei[e], dst = ei[N_EDGES+e];
  const __hip_bfloat16* pl = P + (size_t)src*w2 + k*ED;
  const __hip_bfloat16* pr = P + (size_t)dst*w2 + cw + k*ED;
  const float* eap = ea + (size_t)e*ED;
  float s = 0.f;
  #pragma unroll
  for (int j = 0; j < ED; ++j)
    s += eap[j]*(__bfloat162float(pl[j]) + __bfloat162float(pr[j]));
  int kg = kb + k;
  bi[(size_t)e*KP + kg] = __float2bfloat16(s + bbi[kg]);
}

// ---------- final tiny GEMV + sigmoid ----------
__global__ void out_k(const __hip_bfloat16* __restrict__ m2, const float* __restrict__ Wm3,
                      const float* __restrict__ bm3, float* __restrict__ out){
  int n = blockIdx.x*256 + threadIdx.x;
  if (n >= N_EDGES) return;
  float acc = bm3[0];
  #pragma unroll
  for (int j = 0; j < 32; ++j) acc += __bfloat162float(m2[(size_t)n*128 + j])*Wm3[j];
  out[n] = 1.0f/(1.0f + __expf(-acc));
}

extern "C" void kernel_launch(void* const* d_in, const int* in_sizes, int n_in,
                              void* d_out, int out_size, void* d_ws, size_t ws_size,
                              hipStream_t stream) {
  const float* x   = (const float*)d_in[0];
  const float* ea  = (const float*)d_in[1];
  const int*   ei  = (const int*)d_in[2];
  const float* Wl[4]  = {(const float*)d_in[3],(const float*)d_in[8],(const float*)d_in[13],(const float*)d_in[18]};
  const float* Wr[4]  = {(const float*)d_in[4],(const float*)d_in[9],(const float*)d_in[14],(const float*)d_in[19]};
  const float* We[4]  = {(const float*)d_in[5],(const float*)d_in[10],(const float*)d_in[15],(const float*)d_in[20]};
  const float* att[4] = {(const float*)d_in[6],(const float*)d_in[11],(const float*)d_in[16],(const float*)d_in[21]};
  const float* bia[4] = {(const float*)d_in[7],(const float*)d_in[12],(const float*)d_in[17],(const float*)d_in[22]};
  const float* Wbi = (const float*)d_in[23];
  const float* bbi = (const float*)d_in[24];
  const float* Wm1 = (const float*)d_in[25];
  const float* bm1 = (const float*)d_in[26];
  const float* Wm2 = (const float*)d_in[27];
  const float* bm2 = (const float*)d_in[28];
  const float* Wm3 = (const float*)d_in[29];
  const float* bm3 = (const float*)d_in[30];
  float* out = (float*)d_out;

  char* ws = (char*)d_ws;
  size_t off = 0;
  auto alloc = [&](size_t b){ off = (off + 255) & ~(size_t)255; size_t o = off; off += b; return o; };
  size_t o_bi   = alloc((size_t)M_EDGEP*KP*2);           // 28.90 MB
  size_t o_XLXR = alloc((size_t)M_NODEP*1024*2);         // 20.97 MB
  size_t o_hb   = alloc((size_t)M_NODEP*512*2);          // 10.49 MB
  size_t o_eab  = alloc((size_t)E_AUGP*32*2);            // 3.85 MB
  size_t o_WTa  = alloc((size_t)1327104*2);              // 2.65 MB
  size_t o_WeTa = alloc((size_t)57344*2);
  size_t o_WtA  = alloc((size_t)8704*512*2);             // 8.91 MB
  size_t o_EEP  = alloc((size_t)90000000);               // EE (61.6) | P-chunk (89.1) | m1,m2
  size_t o_Wm1T = alloc((size_t)384*KP*2);
  size_t o_Wm2T = alloc((size_t)128*KP*2);
  size_t o_bm1p = alloc(384*4);
  size_t o_bm2p = alloc(128*4);
  size_t o_ma   = alloc((size_t)N_NODES*ED*4);
  size_t o_cnt  = alloc(40000);
  size_t o_rp   = alloc(40004);
  size_t o_fill = alloc(40000);
  size_t o_csr  = alloc(240000);
  if (off > ws_size){
    fprintf(stderr, "kernel_launch: workspace too small: need %zu have %zu\n", off, ws_size);
    return;
  }

  float* meanat = (float*)(ws + o_ma);
  float* cntF   = (float*)(ws + o_cnt);
  int*   rowptr = (int*)(ws + o_rp);
  int*   fill   = (int*)(ws + o_fill);
  int*   csr    = (int*)(ws + o_csr);
  __hip_bfloat16* XLXR = (__hip_bfloat16*)(ws + o_XLXR);
  __hip_bfloat16* hb   = (__hip_bfloat16*)(ws + o_hb);
  __hip_bfloat16* eab  = (__hip_bfloat16*)(ws + o_eab);
  __hip_bfloat16* WTa  = (__hip_bfloat16*)(ws + o_WTa);
  __hip_bfloat16* WeTa = (__hip_bfloat16*)(ws + o_WeTa);
  __hip_bfloat16* WtA  = (__hip_bfloat16*)(ws + o_WtA);
  __half*        EE    = (__half*)(ws + o_EEP);
  __hip_bfloat16* P    = (__hip_bfloat16*)(ws + o_EEP);
  __hip_bfloat16* Wm1T = (__hip_bfloat16*)(ws + o_Wm1T);
  __hip_bfloat16* Wm2T = (__hip_bfloat16*)(ws + o_Wm2T);
  float* bm1p = (float*)(ws + o_bm1p);
  float* bm2p = (float*)(ws + o_bm2p);
  __hip_bfloat16* bi = (__hip_bfloat16*)(ws + o_bi);
  __hip_bfloat16* m1 = (__hip_bfloat16*)(ws + o_EEP);
  __hip_bfloat16* m2 = (__hip_bfloat16*)(ws + o_EEP + 40000000);

  // mean_attr + CSR build
  hipMemsetAsync(ws + o_ma, 0, (o_cnt - o_ma) + 40000, stream);
  hipMemsetAsync(ws + o_fill, 0, 40000, stream);
  edge_attr_sum_k<<<3125, 256, 0, stream>>>(ea, ei, meanat, cntF);
  mean_div_k<<<625, 256, 0, stream>>>(meanat, cntF);
  scan_k<<<1, 1024, 0, stream>>>(cntF, rowptr);
  scatter_k<<<235, 256, 0, stream>>>(ei, rowptr, fill, csr);

  // casts + all weight prep upfront
  cast_h_k<<<(M_NODEP*32 + 255)/256, 256, 0, stream>>>(x, hb, 32);
  cast_ea_k<<<(E_AUGP*32 + 255)/256, 256, 0, stream>>>(ea, meanat, eab);
  prep_weights_k<<<5184, 256, 0, stream>>>(
      Wl[0], Wr[0], We[0], Wl[1], Wr[1], We[1], Wl[2], Wr[2], We[2], Wl[3], Wr[3], We[3],
      Wm1, bm1, Wm2, bm2, WTa, WeTa, Wm1T, Wm2T, bm1p, bm2p);
  wbi_transpose_k<<<(BI_OUT*1024*ED + 255)/256, 256, 0, stream>>>(Wbi, WtA);

  const int dins[4]  = {32, 256, 512, 512};
  const int douts[4] = {256, 512, 512, 512};
  const int wtOff[4] = {0, 16384, 278528, 802816};
  const int weOff[4] = {0, 8192, 24576, 40960};
  for (int L = 0; L < 4; ++L){
    int din = dins[L], dn = douts[L];
    dim3 g1(M_NODEP/128, 2*dn/128);
    mfma_gemm_k<__hip_bfloat16,false,false><<<g1, 256, 0, stream>>>(
        hb, WTa + wtOff[L], XLXR, nullptr, N_NODES, din, din, 2*dn);
    dim3 ge(E_AUGP/128, dn/128);
    mfma_gemm_k<__half,false,false><<<ge, 256, 0, stream>>>(
        eab, WeTa + weOff[L], EE, nullptr, E_AUG, 32, 32, dn);
    if (dn == 256)
      gat_fused_k<256,true><<<2500, 256, 0, stream>>>(XLXR, EE, ei, rowptr, csr, att[L], bia[L], hb);
    else if (L == 3)
      gat_fused_k<512,false><<<2500, 256, 0, stream>>>(XLXR, EE, ei, rowptr, csr, att[L], bia[L], hb);
    else
      gat_fused_k<512,true><<<2500, 256, 0, stream>>>(XLXR, EE, ei, rowptr, csr, att[L], bia[L], hb);
  }
  // hb holds final node embeddings [M_NODEP x 512] bf16

  // merged PL|PR GEMM per chunk (2 chunks of 136 k's): N = 4352, then bilinear
  const int kbs[2]      = {0, 136};
  const int kcnts[2]    = {136, 136};
  const size_t baseE[2] = {0, 2228224};        // chunk elem offsets in WtA (4352*512)
  for (int c = 0; c < 2; ++c){
    int cw = kcnts[c]*ED, w2 = 2*cw;           // 2176 / 4352
    dim3 gp(M_NODEP/128, w2/128);
    mfma_gemm_k<__hip_bfloat16,false,false><<<gp, 256, 0, stream>>>(
        hb, WtA + baseE[c], P, nullptr, N_NODES, 512, 512, w2);
    bi_k<<<(E_AUG*kcnts[c] + 255)/256, 256, 0, stream>>>(P, ea, ei, csr, bbi, bi, kbs[c], kcnts[c]);
  }

  dim3 gm1(M_EDGEP/128, 3);
  mfma_gemm_k<__hip_bfloat16,true,true><<<gm1, 256, 0, stream>>>(bi, Wm1T, m1, bm1p, M_EDGEP, KP, KP, 384);
  dim3 gm2(M_EDGEP/128, 1);
  mfma_gemm_k<__hip_bfloat16,true,true><<<gm2, 256, 0, stream>>>(m1, Wm2T, m2, bm2p, M_EDGEP, KP, 384, 128);
  out_k<<<(N_EDGES + 255)/256, 256, 0, stream>>>(m2, Wm3, bm3, out);
}